// Round 12
// baseline (202.157 us; speedup 1.0000x reference)
//
#include <hip/hip_runtime.h>
#include <hip/hip_bf16.h>
#include <math.h>

typedef __bf16 bf16x8 __attribute__((ext_vector_type(8)));
typedef __bf16 bf16x4 __attribute__((ext_vector_type(4)));
typedef float f32x4 __attribute__((ext_vector_type(4)));
typedef float f32x16 __attribute__((ext_vector_type(16)));

#define N_TOK 4096
#define EDIM 512
#define NHEAD 8
#define HD 64
#define LDCOMB 896
#define NBIN 100
#define SPLITK 8
#define BK 64
#define NQT 32   // 128-row q tiles

// prep block partition (cvt blocks process 4 float4s per thread)
#define NU_CVT 816
#define NU_TC 64
#define NU_ADD 128
#define NU_TMAT 128
#define NB_PREP (NU_CVT + NU_TC + NU_ADD + NU_TMAT + 1)

__device__ __forceinline__ unsigned int pk2(float a, float b) {
    union { __bf16 h[2]; unsigned int u; } x;
    x.h[0] = (__bf16)a; x.h[1] = (__bf16)b;
    return x.u;
}

// ---------------- prep: cvt + w_out^T + add2 + time-matrix + sort/plan ----------------
__global__ __launch_bounds__(256) void prep_kernel(
    const float* __restrict__ x, const float* __restrict__ w_in,
    const float* __restrict__ w_mlp, const float* __restrict__ w_out,
    const float* __restrict__ status, const float* __restrict__ out_b,
    const float* __restrict__ mlp_b, const int* __restrict__ steps,
    __bf16* __restrict__ x_bf, __bf16* __restrict__ wqkv_bf,
    __bf16* __restrict__ wmlp_bf, __bf16* __restrict__ woutT_bf,
    float* __restrict__ add2, __bf16* __restrict__ tmat,
    int* __restrict__ perm, int* __restrict__ sstep,
    int* __restrict__ bs_row, int* __restrict__ qinfo) {
    __shared__ float T[64][65];
    __shared__ int hist[NBIN];
    __shared__ int offs[NBIN];
    const int bid = blockIdx.x;
    const int tid = threadIdx.x;
    const int wave = tid >> 6, lane = tid & 63;

    if (bid < NU_CVT) {
        // fp32 -> bf16: x, w_in, w_mlp — 4 float4s per thread (816*1024 = exact total)
        const int n0 = N_TOK * EDIM / 4;
        const int n1 = 3 * EDIM * EDIM / 4;
        #pragma unroll
        for (int k = 0; k < 4; k++) {
            int i = bid * 1024 + k * 256 + tid;
            const float* src; __bf16* dst;
            if (i < n0)           { src = x; dst = x_bf; }
            else if (i < n0 + n1) { i -= n0; src = w_in; dst = wqkv_bf; }
            else                  { i -= n0 + n1; src = w_mlp; dst = wmlp_bf; }
            const float4 v = ((const float4*)src)[i];
            bf16x4 o;
            o[0] = (__bf16)v.x; o[1] = (__bf16)v.y; o[2] = (__bf16)v.z; o[3] = (__bf16)v.w;
            ((bf16x4*)dst)[i] = o;
        }
    } else if (bid < NU_CVT + NU_TC) {
        // transpose+cvt w_out -> woutT[k][m]
        const int b2 = bid - NU_CVT;
        const int m0 = (b2 >> 3) * 64, k0 = (b2 & 7) * 64;
        const int row = tid >> 2, c4 = (tid & 3) * 16;
        #pragma unroll
        for (int i = 0; i < 4; i++) {
            const float4 v = *(const float4*)&w_out[(size_t)(m0 + row) * EDIM + k0 + c4 + i * 4];
            T[row][c4 + i * 4 + 0] = v.x;
            T[row][c4 + i * 4 + 1] = v.y;
            T[row][c4 + i * 4 + 2] = v.z;
            T[row][c4 + i * 4 + 3] = v.w;
        }
        __syncthreads();
        const int kr = tid >> 2, m16 = (tid & 3) * 16;
        bf16x8 o0, o1;
        #pragma unroll
        for (int i = 0; i < 8; i++) o0[i] = (__bf16)T[m16 + i][kr];
        #pragma unroll
        for (int i = 0; i < 8; i++) o1[i] = (__bf16)T[m16 + 8 + i][kr];
        *(bf16x8*)&woutT_bf[(size_t)(k0 + kr) * EDIM + m0 + m16] = o0;
        *(bf16x8*)&woutT_bf[(size_t)(k0 + kr) * EDIM + m0 + m16 + 8] = o1;
    } else if (bid < NU_CVT + NU_TC + NU_ADD) {
        // add2[m][j] = status[m].w_mlp[j,512:640] + mlp_b[j] + w_mlp[j,:512].b_out
        const int j = (bid - NU_CVT - NU_TC) * 4 + wave;
        const float* wr = w_mlp + (size_t)j * LDCOMB;
        const int k8 = lane * 8;
        const float4 wa = *(const float4*)&wr[k8], wb = *(const float4*)&wr[k8 + 4];
        const float4 oa = *(const float4*)&out_b[k8], ob = *(const float4*)&out_b[k8 + 4];
        float b = wa.x * oa.x + wa.y * oa.y + wa.z * oa.z + wa.w * oa.w +
                  wb.x * ob.x + wb.y * ob.y + wb.z * ob.z + wb.w * ob.w;
        const int c2 = lane * 2;
        const float w0 = wr[EDIM + c2], w1 = wr[EDIM + c2 + 1];
        float s0 = status[c2] * w0 + status[c2 + 1] * w1;
        float s1 = status[128 + c2] * w0 + status[129 + c2] * w1;
        #pragma unroll
        for (int m = 1; m < 64; m <<= 1) {
            b += __shfl_xor(b, m);
            s0 += __shfl_xor(s0, m);
            s1 += __shfl_xor(s1, m);
        }
        if (lane == 0) {
            const float bb = b + mlp_b[j];
            add2[j] = s0 + bb;
            add2[EDIM + j] = s1 + bb;
        }
    } else if (bid < NU_CVT + NU_TC + NU_ADD + NU_TMAT) {
        // bf16 time matrix [128][256] (rows >= 100 are padding, masked at tv store)
        const int st = bid - NU_CVT - NU_TC - NU_ADD;
        const int c = tid;
        const int pp = c >> 1;
        const float div = expf((float)(2 * pp) * (-9.210340371976184f / 256.0f));
        const float ang = (float)st * div;
        tmat[st * 256 + c] = (__bf16)((c & 1) ? cosf(ang) : sinf(ang));
    } else {
        // counting sort by step + bs_row + per-qtile plan
        if (tid < NBIN) hist[tid] = 0;
        __syncthreads();
        for (int i = tid; i < N_TOK; i += 256)
            atomicAdd(&hist[min(max(steps[i], 0), NBIN - 1)], 1);
        __syncthreads();
        if (tid == 0) {
            int acc = 0;
            for (int s = 0; s < NBIN; s++) { offs[s] = acc; acc += hist[s]; }
        }
        __syncthreads();
        if (tid < NBIN) hist[tid] = offs[tid];   // immutable copy of bin_start
        __syncthreads();
        for (int i = tid; i < N_TOK; i += 256) {
            const int s = min(max(steps[i], 0), NBIN - 1);
            const int pos = atomicAdd(&offs[s], 1);
            perm[pos] = i;
            sstep[pos] = s;
        }
        __syncthreads();
        for (int q = tid; q < N_TOK; q += 256)
            bs_row[q] = hist[sstep[q]];
        __syncthreads();
        for (int qt = tid; qt < NQT; qt += 256) {
            qinfo[qt * 2] = bs_row[qt * 128] & ~(BK - 1);
            qinfo[qt * 2 + 1] = bs_row[qt * 128 + 127];
        }
    }
}

// ---------------- merged GEMMs v3: BK=64, XOR-swizzled LDS, DMA staging, double-buffered ----------------
// qkv->sorted qs/ks/vt (384) + weff (16) + tv (4)
__global__ __launch_bounds__(256) void gemm2_kernel(const __bf16* __restrict__ x_bf,
                                                    const __bf16* __restrict__ wqkv_bf,
                                                    const float* __restrict__ b_in,
                                                    const int* __restrict__ perm,
                                                    __bf16* __restrict__ qs,
                                                    __bf16* __restrict__ ks,
                                                    __bf16* __restrict__ vt,
                                                    const __bf16* __restrict__ wmlp_bf,
                                                    const __bf16* __restrict__ woutT_bf,
                                                    __bf16* __restrict__ weff_bf,
                                                    const __bf16* __restrict__ tmat,
                                                    float* __restrict__ tv) {
    // AB[buf][0]=A-tile, AB[buf][1]=B-tile: [128 rows][64 k] bf16, chunk c of row r at c^(r&7).
    __shared__ __attribute__((aligned(16))) union {
        __bf16 AB[2][2][128 * 64];
        __bf16 T[128][72];
    } sm;
    __shared__ int pr[128];
    const int bid = blockIdx.x;
    const int tid = threadIdx.x;
    const int wave = tid >> 6, lane = tid & 63;
    const int wm = (wave >> 1) * 64, wn = (wave & 1) * 64;
    const int lr = lane & 15, lq = lane >> 4;

    const __bf16 *A, *B;
    int lda, ldb, bm, bn, K, mode;
    if (bid < 384) {
        A = x_bf; lda = EDIM; B = wqkv_bf; ldb = EDIM; K = EDIM; mode = 0;
        bm = (bid & 31) * 128; bn = (bid >> 5) * 128;
        if (tid < 128) pr[tid] = perm[bm + tid];
    } else if (bid < 400) {
        const int b2 = bid - 384;
        A = wmlp_bf; lda = LDCOMB; B = woutT_bf; ldb = EDIM; K = EDIM; mode = 1;
        bm = (b2 & 3) * 128; bn = (b2 >> 2) * 128;
    } else {
        const int b3 = bid - 400;
        A = tmat; lda = 256; B = wmlp_bf + 640; ldb = LDCOMB; K = 256; mode = 2;
        bm = 0; bn = b3 * 128;
    }

    const int ro = lane >> 3;
    const int sc = (lane & 7) ^ ro;

    auto stage = [&](int buf, int k0) {
        #pragma unroll
        for (int i = 0; i < 4; i++) {
            const int g = wave * 4 + i;          // 8-row group 0..15
            const int row = g * 8 + ro;
            const int arow = (mode == 0) ? pr[row] : (bm + row);
            const __bf16* ga = A + (size_t)arow * lda + k0 + sc * 8;
            __builtin_amdgcn_global_load_lds(
                (const __attribute__((address_space(1))) unsigned int*)ga,
                (__attribute__((address_space(3))) unsigned int*)&sm.AB[buf][0][g * 512],
                16, 0, 0);
            const __bf16* gb = B + (size_t)(bn + row) * ldb + k0 + sc * 8;
            __builtin_amdgcn_global_load_lds(
                (const __attribute__((address_space(1))) unsigned int*)gb,
                (__attribute__((address_space(3))) unsigned int*)&sm.AB[buf][1][g * 512],
                16, 0, 0);
        }
    };

    #define GOFF(r, c) (((r) << 6) + ((((c) ^ ((r) & 7))) << 3))

    __syncthreads();            // pr[] visible to all waves before first stage
    f32x4 acc[4][4] = {};
    stage(0, 0);
    __syncthreads();            // tile 0 staged (vmcnt drain at barrier)

    int cur = 0;
    for (int k0 = 0; k0 < K; k0 += 64) {
        if (k0 + 64 < K) stage(cur ^ 1, k0 + 64);   // next tile's DMA overlaps compute
        #pragma unroll
        for (int kk = 0; kk < 2; kk++) {
            bf16x8 af[4], bfr[4];
            #pragma unroll
            for (int i = 0; i < 4; i++) {
                af[i]  = *(const bf16x8*)&sm.AB[cur][0][GOFF(wm + i * 16 + lr, kk * 4 + lq)];
                bfr[i] = *(const bf16x8*)&sm.AB[cur][1][GOFF(wn + i * 16 + lr, kk * 4 + lq)];
            }
            #pragma unroll
            for (int i = 0; i < 4; i++)
                #pragma unroll
                for (int j = 0; j < 4; j++)
                    acc[i][j] = __builtin_amdgcn_mfma_f32_16x16x32_bf16(af[i], bfr[j], acc[i][j], 0, 0, 0);
        }
        __syncthreads();        // drains next-tile DMA + releases cur buffer
        cur ^= 1;
    }
    #undef GOFF

    if (mode == 1) {
        #pragma unroll
        for (int i = 0; i < 4; i++)
            #pragma unroll
            for (int j = 0; j < 4; j++) {
                const int col = bn + wn + j * 16 + lr;
                #pragma unroll
                for (int r = 0; r < 4; r++)
                    weff_bf[(size_t)(bm + wm + i * 16 + lq * 4 + r) * EDIM + col] =
                        (__bf16)acc[i][j][r];
            }
    } else if (mode == 2) {
        #pragma unroll
        for (int i = 0; i < 4; i++)
            #pragma unroll
            for (int j = 0; j < 4; j++) {
                const int col = bn + wn + j * 16 + lr;
                #pragma unroll
                for (int r = 0; r < 4; r++) {
                    const int row = wm + i * 16 + lq * 4 + r;
                    if (row < NBIN) tv[(size_t)row * EDIM + col] = acc[i][j][r];
                }
            }
    } else if (bn < 512) {
        // Q: pre-scale by 1/8*log2(e), sorted rows
        const float SC = 0.125f * 1.44269504f;
        #pragma unroll
        for (int i = 0; i < 4; i++)
            #pragma unroll
            for (int j = 0; j < 4; j++) {
                const int col = bn + wn + j * 16 + lr;
                const float bv = b_in[col];
                #pragma unroll
                for (int r = 0; r < 4; r++)
                    qs[(size_t)(bm + wm + i * 16 + lq * 4 + r) * EDIM + col] =
                        (__bf16)((acc[i][j][r] + bv) * SC);
            }
    } else if (bn < 1024) {
        // K: sorted rows
        #pragma unroll
        for (int i = 0; i < 4; i++)
            #pragma unroll
            for (int j = 0; j < 4; j++) {
                const int col = bn + wn + j * 16 + lr;
                const float bv = b_in[col];
                #pragma unroll
                for (int r = 0; r < 4; r++)
                    ks[(size_t)(bm + wm + i * 16 + lq * 4 + r) * EDIM + (col - 512)] =
                        (__bf16)(acc[i][j][r] + bv);
            }
    } else {
        // V: transpose 128x128 tile via LDS, two 64-col halves -> vt[dim][token]
        #pragma unroll
        for (int half = 0; half < 2; half++) {
            __syncthreads();
            if ((wave & 1) == half) {
                #pragma unroll
                for (int i = 0; i < 4; i++)
                    #pragma unroll
                    for (int j = 0; j < 4; j++) {
                        const float bv = b_in[bn + wn + j * 16 + lr];
                        #pragma unroll
                        for (int r = 0; r < 4; r++)
                            sm.T[wm + i * 16 + lq * 4 + r][j * 16 + lr] =
                                (__bf16)(acc[i][j][r] + bv);
                    }
            }
            __syncthreads();
            for (int u = tid; u < 1024; u += 256) {
                const int d = u & 63, t8 = (u >> 6) * 8;
                bf16x8 v;
                #pragma unroll
                for (int j = 0; j < 8; j++) v[j] = sm.T[t8 + j][d];
                const int dim = (bn - 1024) + half * 64 + d;
                *(bf16x8*)&vt[(size_t)dim * N_TOK + bm + t8] = v;
            }
        }
    }
}

// ---------------- flash attention v6 (R6-verified), split into 2 dispatches along ck
// (visibility: halves top-5 threshold so pool kernels can surface in rocprof) ----------------
__global__ __launch_bounds__(256, 4) void attn_kernel(const __bf16* __restrict__ qs,
                                                      const __bf16* __restrict__ ks,
                                                      const __bf16* __restrict__ vt,
                                                      const int* __restrict__ bs_row,
                                                      const int* __restrict__ qinfo,
                                                      __bf16* __restrict__ po,
                                                      float* __restrict__ pl,
                                                      int ck_base) {
    __shared__ __attribute__((aligned(16))) __bf16 KVs[2][2][4096];

    const int h = blockIdx.x & 7;
    const int qtile = blockIdx.x >> 3;
    const int ck = blockIdx.y + ck_base;
    const int tid = threadIdx.x, wave = tid >> 6, lane = tid & 63;
    const int l31 = lane & 31, hi = lane >> 5;
    const int wq0 = qtile * 128 + wave * 32;

    const int kt0 = qinfo[qtile * 2];
    const int bs_blockmax = qinfo[qtile * 2 + 1];
    const int nt = (N_TOK - kt0) / BK;
    const int kta = kt0 + ((nt * ck) / SPLITK) * BK;
    const int ktb = kt0 + ((nt * (ck + 1)) / SPLITK) * BK;

    bf16x8 aq[4];
    {
        const __bf16* qrow = qs + (size_t)(wq0 + l31) * EDIM + h * HD;
        #pragma unroll
        for (int m = 0; m < 4; m++) aq[m] = *(const bf16x8*)&qrow[m * 16 + hi * 8];
    }
    const int bsq = bs_row[wq0 + l31];

    bf16x8 ones;
    #pragma unroll
    for (int i = 0; i < 8; i++) ones[i] = (__bf16)1.0f;

    f32x16 lacc = {};
    f32x16 o0 = {}, o1 = {};

    const int ro = lane >> 3;
    const int sc = (lane & 7) ^ ro;

    auto stage = [&](int buf, int kt_s) {
        #pragma unroll
        for (int i = 0; i < 2; i++) {
            const int g = wave * 2 + i;
            const __bf16* gk = ks + (size_t)(kt_s + g * 8 + ro) * EDIM + h * HD + sc * 8;
            __builtin_amdgcn_global_load_lds(
                (const __attribute__((address_space(1))) unsigned int*)gk,
                (__attribute__((address_space(3))) unsigned int*)&KVs[buf][0][g * 512],
                16, 0, 0);
            const __bf16* gv = vt + (size_t)(h * HD + g * 8 + ro) * N_TOK + kt_s + sc * 8;
            __builtin_amdgcn_global_load_lds(
                (const __attribute__((address_space(1))) unsigned int*)gv,
                (__attribute__((address_space(3))) unsigned int*)&KVs[buf][1][g * 512],
                16, 0, 0);
        }
    };

    #define LDOFF(r, c) ((r) * 64 + ((((c) ^ ((r) & 7))) << 3))

    if (kta < ktb) stage(0, kta);
    __syncthreads();

    int cur = 0;
    for (int kt = kta; kt < ktb; kt += BK) {
        if (kt + BK < ktb) stage(cur ^ 1, kt + BK);
        const __bf16* Kl = &KVs[cur][0][0];
        const __bf16* Vl = &KVs[cur][1][0];

        __builtin_amdgcn_s_setprio(1);
        #pragma unroll
        for (int t = 0; t < 2; t++) {
            f32x16 s = {};
            #pragma unroll
            for (int m = 0; m < 4; m++) {
                const bf16x8 kb = *(const bf16x8*)&Kl[LDOFF(t * 32 + l31, 2 * m + hi)];
                s = __builtin_amdgcn_mfma_f32_32x32x16_bf16(kb, aq[m], s, 0, 0, 0);
            }
            if (kt < bs_blockmax) {
                const int tokb = kt + t * 32 + 4 * hi;
                #pragma unroll
                for (int r = 0; r < 16; r++) {
                    const int tok = tokb + (r & 3) + 8 * (r >> 2);
                    if (tok < bsq) s[r] = -1e9f;
                }
            }
            unsigned int pk[8];
            #pragma unroll
            for (int m = 0; m < 8; m++)
                pk[m] = pk2(exp2f(s[2 * m]), exp2f(s[2 * m + 1]));
            asm("v_permlane32_swap_b32 %0, %1" : "+v"(pk[0]), "+v"(pk[2]));
            asm("v_permlane32_swap_b32 %0, %1" : "+v"(pk[1]), "+v"(pk[3]));
            asm("v_permlane32_swap_b32 %0, %1" : "+v"(pk[4]), "+v"(pk[6]));
            asm("v_permlane32_swap_b32 %0, %1" : "+v"(pk[5]), "+v"(pk[7]));
            union { unsigned int u[4]; bf16x8 v; } f0, f1;
            f0.u[0] = pk[0]; f0.u[1] = pk[1]; f0.u[2] = pk[2]; f0.u[3] = pk[3];
            f1.u[0] = pk[4]; f1.u[1] = pk[5]; f1.u[2] = pk[6]; f1.u[3] = pk[7];
            lacc = __builtin_amdgcn_mfma_f32_32x32x16_bf16(ones, f0.v, lacc, 0, 0, 0);
            lacc = __builtin_amdgcn_mfma_f32_32x32x16_bf16(ones, f1.v, lacc, 0, 0, 0);
            #pragma unroll
            for (int h2 = 0; h2 < 2; h2++) {
                const bf16x8 va = *(const bf16x8*)&Vl[LDOFF(l31, 4 * t + 2 * h2 + hi)];
                const bf16x8 vb = *(const bf16x8*)&Vl[LDOFF(32 + l31, 4 * t + 2 * h2 + hi)];
                const bf16x8 pf = h2 ? f1.v : f0.v;
                o0 = __builtin_amdgcn_mfma_f32_32x32x16_bf16(va, pf, o0, 0, 0, 0);
                o1 = __builtin_amdgcn_mfma_f32_32x32x16_bf16(vb, pf, o1, 0, 0, 0);
            }
        }
        __builtin_amdgcn_s_setprio(0);
        __syncthreads();
        cur ^= 1;
    }
    #undef LDOFF

    __bf16* pob = po + (((size_t)(ck * NHEAD + h) * N_TOK) + wq0 + l31) * HD;
    #pragma unroll
    for (int rg = 0; rg < 4; rg++) {
        bf16x4 ova, ovb;
        #pragma unroll
        for (int r = 0; r < 4; r++) { ova[r] = (__bf16)o0[rg * 4 + r]; ovb[r] = (__bf16)o1[rg * 4 + r]; }
        *(bf16x4*)&pob[rg * 8 + 4 * hi] = ova;
        *(bf16x4*)&pob[32 + rg * 8 + 4 * hi] = ovb;
    }
    if (hi == 0)
        pl[(size_t)(ck * NHEAD + h) * N_TOK + wq0 + l31] = lacc[0];
}

// ---------------- combine split-K partials (x8 vectorized), scatter to ctx ----------------
__global__ __launch_bounds__(256) void combine_kernel(const __bf16* __restrict__ po,
                                                      const float* __restrict__ pl,
                                                      const int* __restrict__ perm,
                                                      __bf16* __restrict__ ctx) {
    const int e = blockIdx.x * 256 + threadIdx.x;   // over 4096*64 col8-groups
    const int q = e >> 6;
    const int col = (e & 63) * 8;
    const int h = col >> 6, d = col & 63;
    float s[8] = {};
    float l = 0.f;
    #pragma unroll
    for (int c = 0; c < SPLITK; c++) {
        const bf16x8 v = *(const bf16x8*)&po[(((size_t)(c * NHEAD + h) * N_TOK) + q) * HD + d];
        #pragma unroll
        for (int j = 0; j < 8; j++) s[j] += (float)v[j];
        l += pl[(size_t)(c * NHEAD + h) * N_TOK + q];
    }
    const float rl = 1.0f / l;
    bf16x8 o;
    #pragma unroll
    for (int j = 0; j < 8; j++) o[j] = (__bf16)(s[j] * rl);
    *(bf16x8*)&ctx[(size_t)perm[q] * EDIM + col] = o;
}

// ---------------- fused final GEMM v2: 64x128 tiles; bf16 h output ----------------
// h = ctx @ weff^T + add2[dmask] + tv[step]
__global__ __launch_bounds__(256) void gemm_fused(const __bf16* __restrict__ A,
                                                  const __bf16* __restrict__ B,
                                                  const int* __restrict__ dmask,
                                                  const int* __restrict__ steps,
                                                  const float* __restrict__ add2,
                                                  const float* __restrict__ tv,
                                                  __bf16* __restrict__ C) {
    __shared__ __attribute__((aligned(16))) __bf16 As[64][40];
    __shared__ __attribute__((aligned(16))) __bf16 Bs[128][40];
    const int tid = threadIdx.x;
    const int wave = tid >> 6, lane = tid & 63;
    const int wm = (wave >> 1) * 32, wn = (wave & 1) * 64;
    const int bm = blockIdx.x * 64, bn = blockIdx.y * 128;
    const int lr = lane & 15, lq = lane >> 4;

    f32x4 acc[2][4] = {};
    for (int k0 = 0; k0 < EDIM; k0 += 32) {
        __syncthreads();
        {
            const int row = tid >> 2, k8 = (tid & 3) * 8;
            *(bf16x8*)&As[row][k8] = *(const bf16x8*)&A[(size_t)(bm + row) * EDIM + k0 + k8];
        }
        #pragma unroll
        for (int c = tid; c < 512; c += 256) {
            const int row = c >> 2, k8 = (c & 3) * 8;
            *(bf16x8*)&Bs[row][k8] = *(const bf16x8*)&B[(size_t)(bn + row) * EDIM + k0 + k8];
        }
        __syncthreads();
        bf16x8 af[2], bfr[4];
        #pragma unroll
        for (int i = 0; i < 2; i++) af[i] = *(const bf16x8*)&As[wm + i * 16 + lr][lq * 8];
        #pragma unroll
        for (int j = 0; j < 4; j++) bfr[j] = *(const bf16x8*)&Bs[wn + j * 16 + lr][lq * 8];
        #pragma unroll
        for (int i = 0; i < 2; i++)
            #pragma unroll
            for (int j = 0; j < 4; j++)
                acc[i][j] = __builtin_amdgcn_mfma_f32_16x16x32_bf16(af[i], bfr[j], acc[i][j], 0, 0, 0);
    }

    int dmr[2][4], str[2][4];
    #pragma unroll
    for (int i = 0; i < 2; i++)
        #pragma unroll
        for (int r = 0; r < 4; r++) {
            const int row = bm + wm + i * 16 + lq * 4 + r;
            dmr[i][r] = dmask[row];
            str[i][r] = min(max(steps[row], 0), NBIN - 1);
        }
    #pragma unroll
    for (int i = 0; i < 2; i++)
        #pragma unroll
        for (int j = 0; j < 4; j++) {
            const int col = bn + wn + j * 16 + lr;
            #pragma unroll
            for (int r = 0; r < 4; r++) {
                const int row = bm + wm + i * 16 + lq * 4 + r;
                C[(size_t)row * EDIM + col] = (__bf16)(acc[i][j][r]
                    + add2[dmr[i][r] * EDIM + col] + tv[str[i][r] * EDIM + col]);
            }
        }
}

// ---------------- LayerNorm + ReLU + residual (bf16 h input) ----------------
__global__ __launch_bounds__(256) void ln_kernel(const __bf16* __restrict__ h,
                                                 const float* __restrict__ x,
                                                 const float* __restrict__ gamma,
                                                 const float* __restrict__ beta,
                                                 float* __restrict__ out) {
    const int row = blockIdx.x * 4 + (threadIdx.x >> 6);
    const int lane = threadIdx.x & 63;
    const __bf16* hr = h + (size_t)row * EDIM;
    const bf16x8 hv = *(const bf16x8*)&hr[lane * 8];
    float f[8];
    float sum = 0.f, sq = 0.f;
    #pragma unroll
    for (int i = 0; i < 8; i++) {
        f[i] = (float)hv[i];
        sum += f[i];
        sq += f[i] * f[i];
    }
    #pragma unroll
    for (int m = 1; m < 64; m <<= 1) {
        sum += __shfl_xor(sum, m);
        sq  += __shfl_xor(sq, m);
    }
    const float mean = sum * (1.0f / EDIM);
    const float var = sq * (1.0f / EDIM) - mean * mean;
    const float rstd = rsqrtf(var + 1e-5f);
    const float* xr = x + (size_t)row * EDIM;
    float* orow = out + (size_t)row * EDIM;
    const int cb = lane * 8;
    const float4 x0 = *(const float4*)&xr[cb];
    const float4 x1 = *(const float4*)&xr[cb + 4];
    float4 r0, r1;
    {
        float t;
        t = (f[0] - mean) * rstd * gamma[cb + 0] + beta[cb + 0]; r0.x = x0.x + fmaxf(t, 0.f);
        t = (f[1] - mean) * rstd * gamma[cb + 1] + beta[cb + 1]; r0.y = x0.y + fmaxf(t, 0.f);
        t = (f[2] - mean) * rstd * gamma[cb + 2] + beta[cb + 2]; r0.z = x0.z + fmaxf(t, 0.f);
        t = (f[3] - mean) * rstd * gamma[cb + 3] + beta[cb + 3]; r0.w = x0.w + fmaxf(t, 0.f);
        t = (f[4] - mean) * rstd * gamma[cb + 4] + beta[cb + 4]; r1.x = x1.x + fmaxf(t, 0.f);
        t = (f[5] - mean) * rstd * gamma[cb + 5] + beta[cb + 5]; r1.y = x1.y + fmaxf(t, 0.f);
        t = (f[6] - mean) * rstd * gamma[cb + 6] + beta[cb + 6]; r1.z = x1.z + fmaxf(t, 0.f);
        t = (f[7] - mean) * rstd * gamma[cb + 7] + beta[cb + 7]; r1.w = x1.w + fmaxf(t, 0.f);
    }
    *(float4*)&orow[cb] = r0;
    *(float4*)&orow[cb + 4] = r1;
}

// ---------------- launch ----------------
extern "C" void kernel_launch(void* const* d_in, const int* in_sizes, int n_in,
                              void* d_out, int out_size, void* d_ws, size_t ws_size,
                              hipStream_t stream) {
    const float* x      = (const float*)d_in[0];
    const int*   dmask  = (const int*)d_in[1];
    const int*   steps  = (const int*)d_in[2];
    const float* status = (const float*)d_in[3];
    const float* w_in   = (const float*)d_in[4];
    const float* b_in   = (const float*)d_in[5];
    const float* w_out  = (const float*)d_in[6];
    const float* b_out  = (const float*)d_in[7];
    const float* w_mlp  = (const float*)d_in[8];
    const float* b_mlp  = (const float*)d_in[9];
    const float* gamma  = (const float*)d_in[10];
    const float* beta   = (const float*)d_in[11];
    float* out = (float*)d_out;

    char* ws = (char*)d_ws;
    size_t off = 0;
    auto alloc = [&](size_t bytes) {
        void* ptr = ws + off;
        off = (off + bytes + 255) & ~(size_t)255;
        return ptr;
    };
    __bf16* x_bf    = (__bf16*)alloc((size_t)N_TOK * EDIM * 2);
    __bf16* wqkv_bf = (__bf16*)alloc((size_t)3 * EDIM * EDIM * 2);
    __bf16* wmlp_bf = (__bf16*)alloc((size_t)EDIM * LDCOMB * 2);
    __bf16* woutT_bf= (__bf16*)alloc((size_t)EDIM * EDIM * 2);
    __bf16* weff_bf = (__bf16*)alloc((size_t)EDIM * EDIM * 2);
    __bf16* qs_bf   = (__bf16*)alloc((size_t)N_TOK * EDIM * 2);
    __bf16* ks_bf   = (__bf16*)alloc((size_t)N_TOK * EDIM * 2);
    __bf16* vt_bf   = (__bf16*)alloc((size_t)EDIM * N_TOK * 2);
    __bf16* ctx_bf  = (__bf16*)alloc((size_t)N_TOK * EDIM * 2);
    __bf16* h_bf    = (__bf16*)alloc((size_t)N_TOK * EDIM * 2);
    int*    perm    = (int*)alloc(N_TOK * 4);
    int*    sstep   = (int*)alloc(N_TOK * 4);
    int*    bs_row  = (int*)alloc(N_TOK * 4);
    int*    qinfo   = (int*)alloc(128 * 4);
    __bf16* po      = (__bf16*)alloc((size_t)SPLITK * NHEAD * N_TOK * HD * 2);
    float*  pl      = (float*)alloc((size_t)SPLITK * NHEAD * N_TOK * 4);
    float*  add2    = (float*)alloc(2 * EDIM * 4);
    float*  tv      = (float*)alloc((size_t)NBIN * EDIM * 4);
    __bf16* tmat    = (__bf16*)alloc(128 * 256 * 2);

    // prep: converts + w_out^T + add2 + time-matrix + sort/plan
    prep_kernel<<<NB_PREP, 256, 0, stream>>>(
        x, w_in, w_mlp, w_out, status, b_out, b_mlp, steps,
        x_bf, wqkv_bf, wmlp_bf, woutT_bf, add2, tmat, perm, sstep, bs_row, qinfo);
    // qkv GEMM (direct sorted qs/ks/vt) + weff GEMM + tv GEMM (double-buffered)
    gemm2_kernel<<<404, 256, 0, stream>>>(
        x_bf, wqkv_bf, b_in, perm, qs_bf, ks_bf, vt_bf,
        wmlp_bf, woutT_bf, weff_bf, tmat, tv);
    // attention split into two half-SPLITK dispatches (visibility + identical math)
    attn_kernel<<<dim3(NQT * NHEAD, SPLITK / 2), 256, 0, stream>>>(
        qs_bf, ks_bf, vt_bf, bs_row, qinfo, po, pl, 0);
    attn_kernel<<<dim3(NQT * NHEAD, SPLITK / 2), 256, 0, stream>>>(
        qs_bf, ks_bf, vt_bf, bs_row, qinfo, po, pl, SPLITK / 2);
    // combine partials -> ctx (original token order, x8 vectorized)
    combine_kernel<<<(N_TOK * EDIM) / 2048, 256, 0, stream>>>(po, pl, perm, ctx_bf);
    // h = ctx @ w_eff^T + add2[dmask] + tv[step]  (64x128 tiles, bf16 out)
    gemm_fused<<<dim3(N_TOK / 64, EDIM / 128), 256, 0, stream>>>(
        ctx_bf, weff_bf, dmask, steps, add2, tv, h_bf);
    // LN + ReLU + residual (bf16 h input)
    ln_kernel<<<N_TOK / 4, 256, 0, stream>>>(h_bf, x, gamma, beta, out);
}

// Round 13
// 181.083 us; speedup vs baseline: 1.1164x; 1.1164x over previous
//
#include <hip/hip_runtime.h>
#include <hip/hip_bf16.h>
#include <math.h>

typedef __bf16 bf16x8 __attribute__((ext_vector_type(8)));
typedef __bf16 bf16x4 __attribute__((ext_vector_type(4)));
typedef float f32x4 __attribute__((ext_vector_type(4)));
typedef float f32x16 __attribute__((ext_vector_type(16)));

#define N_TOK 4096
#define EDIM 512
#define NHEAD 8
#define HD 64
#define LDCOMB 896
#define NBIN 100
#define SPLITK 8
#define BK 64
#define NQT 32   // 128-row q tiles

// prep block partition (cvt blocks process 4 float4s per thread)
#define NU_CVT 816
#define NU_TC 64
#define NU_ADD 128
#define NU_TMAT 128
#define NB_PREP (NU_CVT + NU_TC + NU_ADD + NU_TMAT + 1)

__device__ __forceinline__ unsigned int pk2(float a, float b) {
    union { __bf16 h[2]; unsigned int u; } x;
    x.h[0] = (__bf16)a; x.h[1] = (__bf16)b;
    return x.u;
}

// ---------------- prep: cvt + w_out^T + add2 + time-matrix + sort/plan ----------------
__global__ __launch_bounds__(256) void prep_kernel(
    const float* __restrict__ x, const float* __restrict__ w_in,
    const float* __restrict__ w_mlp, const float* __restrict__ w_out,
    const float* __restrict__ status, const float* __restrict__ out_b,
    const float* __restrict__ mlp_b, const int* __restrict__ steps,
    __bf16* __restrict__ x_bf, __bf16* __restrict__ wqkv_bf,
    __bf16* __restrict__ wmlp_bf, __bf16* __restrict__ woutT_bf,
    float* __restrict__ add2, __bf16* __restrict__ tmat,
    int* __restrict__ perm, int* __restrict__ sstep,
    int* __restrict__ bs_row, int* __restrict__ qinfo) {
    __shared__ float T[64][65];
    __shared__ int hist[NBIN];
    __shared__ int offs[NBIN];
    const int bid = blockIdx.x;
    const int tid = threadIdx.x;
    const int wave = tid >> 6, lane = tid & 63;

    if (bid < NU_CVT) {
        // fp32 -> bf16: x, w_in, w_mlp — 4 float4s per thread (816*1024 = exact total)
        const int n0 = N_TOK * EDIM / 4;
        const int n1 = 3 * EDIM * EDIM / 4;
        #pragma unroll
        for (int k = 0; k < 4; k++) {
            int i = bid * 1024 + k * 256 + tid;
            const float* src; __bf16* dst;
            if (i < n0)           { src = x; dst = x_bf; }
            else if (i < n0 + n1) { i -= n0; src = w_in; dst = wqkv_bf; }
            else                  { i -= n0 + n1; src = w_mlp; dst = wmlp_bf; }
            const float4 v = ((const float4*)src)[i];
            bf16x4 o;
            o[0] = (__bf16)v.x; o[1] = (__bf16)v.y; o[2] = (__bf16)v.z; o[3] = (__bf16)v.w;
            ((bf16x4*)dst)[i] = o;
        }
    } else if (bid < NU_CVT + NU_TC) {
        // transpose+cvt w_out -> woutT[k][m]
        const int b2 = bid - NU_CVT;
        const int m0 = (b2 >> 3) * 64, k0 = (b2 & 7) * 64;
        const int row = tid >> 2, c4 = (tid & 3) * 16;
        #pragma unroll
        for (int i = 0; i < 4; i++) {
            const float4 v = *(const float4*)&w_out[(size_t)(m0 + row) * EDIM + k0 + c4 + i * 4];
            T[row][c4 + i * 4 + 0] = v.x;
            T[row][c4 + i * 4 + 1] = v.y;
            T[row][c4 + i * 4 + 2] = v.z;
            T[row][c4 + i * 4 + 3] = v.w;
        }
        __syncthreads();
        const int kr = tid >> 2, m16 = (tid & 3) * 16;
        bf16x8 o0, o1;
        #pragma unroll
        for (int i = 0; i < 8; i++) o0[i] = (__bf16)T[m16 + i][kr];
        #pragma unroll
        for (int i = 0; i < 8; i++) o1[i] = (__bf16)T[m16 + 8 + i][kr];
        *(bf16x8*)&woutT_bf[(size_t)(k0 + kr) * EDIM + m0 + m16] = o0;
        *(bf16x8*)&woutT_bf[(size_t)(k0 + kr) * EDIM + m0 + m16 + 8] = o1;
    } else if (bid < NU_CVT + NU_TC + NU_ADD) {
        // add2[m][j] = status[m].w_mlp[j,512:640] + mlp_b[j] + w_mlp[j,:512].b_out
        const int j = (bid - NU_CVT - NU_TC) * 4 + wave;
        const float* wr = w_mlp + (size_t)j * LDCOMB;
        const int k8 = lane * 8;
        const float4 wa = *(const float4*)&wr[k8], wb = *(const float4*)&wr[k8 + 4];
        const float4 oa = *(const float4*)&out_b[k8], ob = *(const float4*)&out_b[k8 + 4];
        float b = wa.x * oa.x + wa.y * oa.y + wa.z * oa.z + wa.w * oa.w +
                  wb.x * ob.x + wb.y * ob.y + wb.z * ob.z + wb.w * ob.w;
        const int c2 = lane * 2;
        const float w0 = wr[EDIM + c2], w1 = wr[EDIM + c2 + 1];
        float s0 = status[c2] * w0 + status[c2 + 1] * w1;
        float s1 = status[128 + c2] * w0 + status[129 + c2] * w1;
        #pragma unroll
        for (int m = 1; m < 64; m <<= 1) {
            b += __shfl_xor(b, m);
            s0 += __shfl_xor(s0, m);
            s1 += __shfl_xor(s1, m);
        }
        if (lane == 0) {
            const float bb = b + mlp_b[j];
            add2[j] = s0 + bb;
            add2[EDIM + j] = s1 + bb;
        }
    } else if (bid < NU_CVT + NU_TC + NU_ADD + NU_TMAT) {
        // bf16 time matrix [128][256] (rows >= 100 are padding, masked at tv store)
        const int st = bid - NU_CVT - NU_TC - NU_ADD;
        const int c = tid;
        const int pp = c >> 1;
        const float div = expf((float)(2 * pp) * (-9.210340371976184f / 256.0f));
        const float ang = (float)st * div;
        tmat[st * 256 + c] = (__bf16)((c & 1) ? cosf(ang) : sinf(ang));
    } else {
        // counting sort by step + bs_row + per-qtile plan
        if (tid < NBIN) hist[tid] = 0;
        __syncthreads();
        for (int i = tid; i < N_TOK; i += 256)
            atomicAdd(&hist[min(max(steps[i], 0), NBIN - 1)], 1);
        __syncthreads();
        if (tid == 0) {
            int acc = 0;
            for (int s = 0; s < NBIN; s++) { offs[s] = acc; acc += hist[s]; }
        }
        __syncthreads();
        if (tid < NBIN) hist[tid] = offs[tid];   // immutable copy of bin_start
        __syncthreads();
        for (int i = tid; i < N_TOK; i += 256) {
            const int s = min(max(steps[i], 0), NBIN - 1);
            const int pos = atomicAdd(&offs[s], 1);
            perm[pos] = i;
            sstep[pos] = s;
        }
        __syncthreads();
        for (int q = tid; q < N_TOK; q += 256)
            bs_row[q] = hist[sstep[q]];
        __syncthreads();
        for (int qt = tid; qt < NQT; qt += 256) {
            qinfo[qt * 2] = bs_row[qt * 128] & ~(BK - 1);
            qinfo[qt * 2 + 1] = bs_row[qt * 128 + 127];
        }
    }
}

// ---------------- merged GEMMs v2: BK=64, XOR-swizzled LDS, global_load_lds staging ----------------
// qkv->sorted qs/ks/vt (384) + weff (16) + tv (4)
__global__ __launch_bounds__(256) void gemm2_kernel(const __bf16* __restrict__ x_bf,
                                                    const __bf16* __restrict__ wqkv_bf,
                                                    const float* __restrict__ b_in,
                                                    const int* __restrict__ perm,
                                                    __bf16* __restrict__ qs,
                                                    __bf16* __restrict__ ks,
                                                    __bf16* __restrict__ vt,
                                                    const __bf16* __restrict__ wmlp_bf,
                                                    const __bf16* __restrict__ woutT_bf,
                                                    __bf16* __restrict__ weff_bf,
                                                    const __bf16* __restrict__ tmat,
                                                    float* __restrict__ tv) {
    // As/Bs: [128 rows][64 k] bf16, chunk c (8 elem) of row r stored at c^(r&7).
    __shared__ __attribute__((aligned(16))) union {
        struct { __bf16 As[128 * 64]; __bf16 Bs[128 * 64]; } g;
        __bf16 T[128][72];
    } sm;
    __shared__ int pr[128];
    const int bid = blockIdx.x;
    const int tid = threadIdx.x;
    const int wave = tid >> 6, lane = tid & 63;
    const int wm = (wave >> 1) * 64, wn = (wave & 1) * 64;
    const int lr = lane & 15, lq = lane >> 4;

    const __bf16 *A, *B;
    int lda, ldb, bm, bn, K, mode;
    if (bid < 384) {
        A = x_bf; lda = EDIM; B = wqkv_bf; ldb = EDIM; K = EDIM; mode = 0;
        bm = (bid & 31) * 128; bn = (bid >> 5) * 128;
        if (tid < 128) pr[tid] = perm[bm + tid];
    } else if (bid < 400) {
        const int b2 = bid - 384;
        A = wmlp_bf; lda = LDCOMB; B = woutT_bf; ldb = EDIM; K = EDIM; mode = 1;
        bm = (b2 & 3) * 128; bn = (b2 >> 2) * 128;
    } else {
        const int b3 = bid - 400;
        A = tmat; lda = 256; B = wmlp_bf + 640; ldb = LDCOMB; K = 256; mode = 2;
        bm = 0; bn = b3 * 128;
    }

    const int ro = lane >> 3;
    const int sc = (lane & 7) ^ ro;

    #define GOFF(r, c) (((r) << 6) + ((((c) ^ ((r) & 7))) << 3))

    f32x4 acc[4][4] = {};
    for (int k0 = 0; k0 < K; k0 += 64) {
        __syncthreads();
        #pragma unroll
        for (int i = 0; i < 4; i++) {
            const int g = wave * 4 + i;          // 8-row group 0..15
            const int row = g * 8 + ro;
            const int arow = (mode == 0) ? pr[row] : (bm + row);
            const __bf16* ga = A + (size_t)arow * lda + k0 + sc * 8;
            __builtin_amdgcn_global_load_lds(
                (const __attribute__((address_space(1))) unsigned int*)ga,
                (__attribute__((address_space(3))) unsigned int*)&sm.g.As[g * 512],
                16, 0, 0);
            const __bf16* gb = B + (size_t)(bn + row) * ldb + k0 + sc * 8;
            __builtin_amdgcn_global_load_lds(
                (const __attribute__((address_space(1))) unsigned int*)gb,
                (__attribute__((address_space(3))) unsigned int*)&sm.g.Bs[g * 512],
                16, 0, 0);
        }
        __syncthreads();
        #pragma unroll
        for (int kk = 0; kk < 2; kk++) {
            bf16x8 af[4], bfr[4];
            #pragma unroll
            for (int i = 0; i < 4; i++) {
                af[i]  = *(const bf16x8*)&sm.g.As[GOFF(wm + i * 16 + lr, kk * 4 + lq)];
                bfr[i] = *(const bf16x8*)&sm.g.Bs[GOFF(wn + i * 16 + lr, kk * 4 + lq)];
            }
            #pragma unroll
            for (int i = 0; i < 4; i++)
                #pragma unroll
                for (int j = 0; j < 4; j++)
                    acc[i][j] = __builtin_amdgcn_mfma_f32_16x16x32_bf16(af[i], bfr[j], acc[i][j], 0, 0, 0);
        }
    }
    #undef GOFF

    if (mode == 1) {
        #pragma unroll
        for (int i = 0; i < 4; i++)
            #pragma unroll
            for (int j = 0; j < 4; j++) {
                const int col = bn + wn + j * 16 + lr;
                #pragma unroll
                for (int r = 0; r < 4; r++)
                    weff_bf[(size_t)(bm + wm + i * 16 + lq * 4 + r) * EDIM + col] =
                        (__bf16)acc[i][j][r];
            }
    } else if (mode == 2) {
        #pragma unroll
        for (int i = 0; i < 4; i++)
            #pragma unroll
            for (int j = 0; j < 4; j++) {
                const int col = bn + wn + j * 16 + lr;
                #pragma unroll
                for (int r = 0; r < 4; r++) {
                    const int row = wm + i * 16 + lq * 4 + r;
                    if (row < NBIN) tv[(size_t)row * EDIM + col] = acc[i][j][r];
                }
            }
    } else if (bn < 512) {
        // Q: pre-scale by 1/8*log2(e), sorted rows
        const float SC = 0.125f * 1.44269504f;
        #pragma unroll
        for (int i = 0; i < 4; i++)
            #pragma unroll
            for (int j = 0; j < 4; j++) {
                const int col = bn + wn + j * 16 + lr;
                const float bv = b_in[col];
                #pragma unroll
                for (int r = 0; r < 4; r++)
                    qs[(size_t)(bm + wm + i * 16 + lq * 4 + r) * EDIM + col] =
                        (__bf16)((acc[i][j][r] + bv) * SC);
            }
    } else if (bn < 1024) {
        // K: sorted rows
        #pragma unroll
        for (int i = 0; i < 4; i++)
            #pragma unroll
            for (int j = 0; j < 4; j++) {
                const int col = bn + wn + j * 16 + lr;
                const float bv = b_in[col];
                #pragma unroll
                for (int r = 0; r < 4; r++)
                    ks[(size_t)(bm + wm + i * 16 + lq * 4 + r) * EDIM + (col - 512)] =
                        (__bf16)(acc[i][j][r] + bv);
            }
    } else {
        // V: transpose 128x128 tile via LDS, two 64-col halves -> vt[dim][token]
        #pragma unroll
        for (int half = 0; half < 2; half++) {
            __syncthreads();
            if ((wave & 1) == half) {
                #pragma unroll
                for (int i = 0; i < 4; i++)
                    #pragma unroll
                    for (int j = 0; j < 4; j++) {
                        const float bv = b_in[bn + wn + j * 16 + lr];
                        #pragma unroll
                        for (int r = 0; r < 4; r++)
                            sm.T[wm + i * 16 + lq * 4 + r][j * 16 + lr] =
                                (__bf16)(acc[i][j][r] + bv);
                    }
            }
            __syncthreads();
            for (int u = tid; u < 1024; u += 256) {
                const int d = u & 63, t8 = (u >> 6) * 8;
                bf16x8 v;
                #pragma unroll
                for (int j = 0; j < 8; j++) v[j] = sm.T[t8 + j][d];
                const int dim = (bn - 1024) + half * 64 + d;
                *(bf16x8*)&vt[(size_t)dim * N_TOK + bm + t8] = v;
            }
        }
    }
}

// ---------------- flash attention v6 (R6-verified): 32x32 MFMA, XOR LDS,
// 2-buffer DMA double-buffer, SPLITK=8, 1 barrier per K-tile ----------------
__global__ __launch_bounds__(256, 4) void attn_kernel(const __bf16* __restrict__ qs,
                                                      const __bf16* __restrict__ ks,
                                                      const __bf16* __restrict__ vt,
                                                      const int* __restrict__ bs_row,
                                                      const int* __restrict__ qinfo,
                                                      __bf16* __restrict__ po,
                                                      float* __restrict__ pl) {
    __shared__ __attribute__((aligned(16))) __bf16 KVs[2][2][4096];

    const int h = blockIdx.x & 7;
    const int qtile = blockIdx.x >> 3;
    const int ck = blockIdx.y;
    const int tid = threadIdx.x, wave = tid >> 6, lane = tid & 63;
    const int l31 = lane & 31, hi = lane >> 5;
    const int wq0 = qtile * 128 + wave * 32;

    const int kt0 = qinfo[qtile * 2];
    const int bs_blockmax = qinfo[qtile * 2 + 1];
    const int nt = (N_TOK - kt0) / BK;
    const int kta = kt0 + ((nt * ck) / SPLITK) * BK;
    const int ktb = kt0 + ((nt * (ck + 1)) / SPLITK) * BK;

    bf16x8 aq[4];
    {
        const __bf16* qrow = qs + (size_t)(wq0 + l31) * EDIM + h * HD;
        #pragma unroll
        for (int m = 0; m < 4; m++) aq[m] = *(const bf16x8*)&qrow[m * 16 + hi * 8];
    }
    const int bsq = bs_row[wq0 + l31];

    bf16x8 ones;
    #pragma unroll
    for (int i = 0; i < 8; i++) ones[i] = (__bf16)1.0f;

    f32x16 lacc = {};
    f32x16 o0 = {}, o1 = {};

    const int ro = lane >> 3;
    const int sc = (lane & 7) ^ ro;

    auto stage = [&](int buf, int kt_s) {
        #pragma unroll
        for (int i = 0; i < 2; i++) {
            const int g = wave * 2 + i;
            const __bf16* gk = ks + (size_t)(kt_s + g * 8 + ro) * EDIM + h * HD + sc * 8;
            __builtin_amdgcn_global_load_lds(
                (const __attribute__((address_space(1))) unsigned int*)gk,
                (__attribute__((address_space(3))) unsigned int*)&KVs[buf][0][g * 512],
                16, 0, 0);
            const __bf16* gv = vt + (size_t)(h * HD + g * 8 + ro) * N_TOK + kt_s + sc * 8;
            __builtin_amdgcn_global_load_lds(
                (const __attribute__((address_space(1))) unsigned int*)gv,
                (__attribute__((address_space(3))) unsigned int*)&KVs[buf][1][g * 512],
                16, 0, 0);
        }
    };

    #define LDOFF(r, c) ((r) * 64 + ((((c) ^ ((r) & 7))) << 3))

    if (kta < ktb) stage(0, kta);
    __syncthreads();

    int cur = 0;
    for (int kt = kta; kt < ktb; kt += BK) {
        if (kt + BK < ktb) stage(cur ^ 1, kt + BK);
        const __bf16* Kl = &KVs[cur][0][0];
        const __bf16* Vl = &KVs[cur][1][0];

        __builtin_amdgcn_s_setprio(1);
        #pragma unroll
        for (int t = 0; t < 2; t++) {
            f32x16 s = {};
            #pragma unroll
            for (int m = 0; m < 4; m++) {
                const bf16x8 kb = *(const bf16x8*)&Kl[LDOFF(t * 32 + l31, 2 * m + hi)];
                s = __builtin_amdgcn_mfma_f32_32x32x16_bf16(kb, aq[m], s, 0, 0, 0);
            }
            if (kt < bs_blockmax) {
                const int tokb = kt + t * 32 + 4 * hi;
                #pragma unroll
                for (int r = 0; r < 16; r++) {
                    const int tok = tokb + (r & 3) + 8 * (r >> 2);
                    if (tok < bsq) s[r] = -1e9f;
                }
            }
            unsigned int pk[8];
            #pragma unroll
            for (int m = 0; m < 8; m++)
                pk[m] = pk2(exp2f(s[2 * m]), exp2f(s[2 * m + 1]));
            asm("v_permlane32_swap_b32 %0, %1" : "+v"(pk[0]), "+v"(pk[2]));
            asm("v_permlane32_swap_b32 %0, %1" : "+v"(pk[1]), "+v"(pk[3]));
            asm("v_permlane32_swap_b32 %0, %1" : "+v"(pk[4]), "+v"(pk[6]));
            asm("v_permlane32_swap_b32 %0, %1" : "+v"(pk[5]), "+v"(pk[7]));
            union { unsigned int u[4]; bf16x8 v; } f0, f1;
            f0.u[0] = pk[0]; f0.u[1] = pk[1]; f0.u[2] = pk[2]; f0.u[3] = pk[3];
            f1.u[0] = pk[4]; f1.u[1] = pk[5]; f1.u[2] = pk[6]; f1.u[3] = pk[7];
            lacc = __builtin_amdgcn_mfma_f32_32x32x16_bf16(ones, f0.v, lacc, 0, 0, 0);
            lacc = __builtin_amdgcn_mfma_f32_32x32x16_bf16(ones, f1.v, lacc, 0, 0, 0);
            #pragma unroll
            for (int h2 = 0; h2 < 2; h2++) {
                const bf16x8 va = *(const bf16x8*)&Vl[LDOFF(l31, 4 * t + 2 * h2 + hi)];
                const bf16x8 vb = *(const bf16x8*)&Vl[LDOFF(32 + l31, 4 * t + 2 * h2 + hi)];
                const bf16x8 pf = h2 ? f1.v : f0.v;
                o0 = __builtin_amdgcn_mfma_f32_32x32x16_bf16(va, pf, o0, 0, 0, 0);
                o1 = __builtin_amdgcn_mfma_f32_32x32x16_bf16(vb, pf, o1, 0, 0, 0);
            }
        }
        __builtin_amdgcn_s_setprio(0);
        __syncthreads();
        cur ^= 1;
    }
    #undef LDOFF

    __bf16* pob = po + (((size_t)(ck * NHEAD + h) * N_TOK) + wq0 + l31) * HD;
    #pragma unroll
    for (int rg = 0; rg < 4; rg++) {
        bf16x4 ova, ovb;
        #pragma unroll
        for (int r = 0; r < 4; r++) { ova[r] = (__bf16)o0[rg * 4 + r]; ovb[r] = (__bf16)o1[rg * 4 + r]; }
        *(bf16x4*)&pob[rg * 8 + 4 * hi] = ova;
        *(bf16x4*)&pob[32 + rg * 8 + 4 * hi] = ovb;
    }
    if (hi == 0)
        pl[(size_t)(ck * NHEAD + h) * N_TOK + wq0 + l31] = lacc[0];
}

// ---------------- combine split-K partials (x8 vectorized), scatter to ctx ----------------
__global__ __launch_bounds__(256) void combine_kernel(const __bf16* __restrict__ po,
                                                      const float* __restrict__ pl,
                                                      const int* __restrict__ perm,
                                                      __bf16* __restrict__ ctx) {
    const int e = blockIdx.x * 256 + threadIdx.x;   // over 4096*64 col8-groups
    const int q = e >> 6;
    const int col = (e & 63) * 8;
    const int h = col >> 6, d = col & 63;
    float s[8] = {};
    float l = 0.f;
    #pragma unroll
    for (int c = 0; c < SPLITK; c++) {
        const bf16x8 v = *(const bf16x8*)&po[(((size_t)(c * NHEAD + h) * N_TOK) + q) * HD + d];
        #pragma unroll
        for (int j = 0; j < 8; j++) s[j] += (float)v[j];
        l += pl[(size_t)(c * NHEAD + h) * N_TOK + q];
    }
    const float rl = 1.0f / l;
    bf16x8 o;
    #pragma unroll
    for (int j = 0; j < 8; j++) o[j] = (__bf16)(s[j] * rl);
    *(bf16x8*)&ctx[(size_t)perm[q] * EDIM + col] = o;
}

// ---------------- fused final GEMM v2: 64x128 tiles; bf16 h output ----------------
// h = ctx @ weff^T + add2[dmask] + tv[step]
__global__ __launch_bounds__(256) void gemm_fused(const __bf16* __restrict__ A,
                                                  const __bf16* __restrict__ B,
                                                  const int* __restrict__ dmask,
                                                  const int* __restrict__ steps,
                                                  const float* __restrict__ add2,
                                                  const float* __restrict__ tv,
                                                  __bf16* __restrict__ C) {
    __shared__ __attribute__((aligned(16))) __bf16 As[64][40];
    __shared__ __attribute__((aligned(16))) __bf16 Bs[128][40];
    const int tid = threadIdx.x;
    const int wave = tid >> 6, lane = tid & 63;
    const int wm = (wave >> 1) * 32, wn = (wave & 1) * 64;
    const int bm = blockIdx.x * 64, bn = blockIdx.y * 128;
    const int lr = lane & 15, lq = lane >> 4;

    f32x4 acc[2][4] = {};
    for (int k0 = 0; k0 < EDIM; k0 += 32) {
        __syncthreads();
        {
            const int row = tid >> 2, k8 = (tid & 3) * 8;
            *(bf16x8*)&As[row][k8] = *(const bf16x8*)&A[(size_t)(bm + row) * EDIM + k0 + k8];
        }
        #pragma unroll
        for (int c = tid; c < 512; c += 256) {
            const int row = c >> 2, k8 = (c & 3) * 8;
            *(bf16x8*)&Bs[row][k8] = *(const bf16x8*)&B[(size_t)(bn + row) * EDIM + k0 + k8];
        }
        __syncthreads();
        bf16x8 af[2], bfr[4];
        #pragma unroll
        for (int i = 0; i < 2; i++) af[i] = *(const bf16x8*)&As[wm + i * 16 + lr][lq * 8];
        #pragma unroll
        for (int j = 0; j < 4; j++) bfr[j] = *(const bf16x8*)&Bs[wn + j * 16 + lr][lq * 8];
        #pragma unroll
        for (int i = 0; i < 2; i++)
            #pragma unroll
            for (int j = 0; j < 4; j++)
                acc[i][j] = __builtin_amdgcn_mfma_f32_16x16x32_bf16(af[i], bfr[j], acc[i][j], 0, 0, 0);
    }

    int dmr[2][4], str[2][4];
    #pragma unroll
    for (int i = 0; i < 2; i++)
        #pragma unroll
        for (int r = 0; r < 4; r++) {
            const int row = bm + wm + i * 16 + lq * 4 + r;
            dmr[i][r] = dmask[row];
            str[i][r] = min(max(steps[row], 0), NBIN - 1);
        }
    #pragma unroll
    for (int i = 0; i < 2; i++)
        #pragma unroll
        for (int j = 0; j < 4; j++) {
            const int col = bn + wn + j * 16 + lr;
            #pragma unroll
            for (int r = 0; r < 4; r++) {
                const int row = bm + wm + i * 16 + lq * 4 + r;
                C[(size_t)row * EDIM + col] = (__bf16)(acc[i][j][r]
                    + add2[dmr[i][r] * EDIM + col] + tv[str[i][r] * EDIM + col]);
            }
        }
}

// ---------------- LayerNorm + ReLU + residual (bf16 h input) ----------------
__global__ __launch_bounds__(256) void ln_kernel(const __bf16* __restrict__ h,
                                                 const float* __restrict__ x,
                                                 const float* __restrict__ gamma,
                                                 const float* __restrict__ beta,
                                                 float* __restrict__ out) {
    const int row = blockIdx.x * 4 + (threadIdx.x >> 6);
    const int lane = threadIdx.x & 63;
    const __bf16* hr = h + (size_t)row * EDIM;
    const bf16x8 hv = *(const bf16x8*)&hr[lane * 8];
    float f[8];
    float sum = 0.f, sq = 0.f;
    #pragma unroll
    for (int i = 0; i < 8; i++) {
        f[i] = (float)hv[i];
        sum += f[i];
        sq += f[i] * f[i];
    }
    #pragma unroll
    for (int m = 1; m < 64; m <<= 1) {
        sum += __shfl_xor(sum, m);
        sq  += __shfl_xor(sq, m);
    }
    const float mean = sum * (1.0f / EDIM);
    const float var = sq * (1.0f / EDIM) - mean * mean;
    const float rstd = rsqrtf(var + 1e-5f);
    const float* xr = x + (size_t)row * EDIM;
    float* orow = out + (size_t)row * EDIM;
    const int cb = lane * 8;
    const float4 x0 = *(const float4*)&xr[cb];
    const float4 x1 = *(const float4*)&xr[cb + 4];
    float4 r0, r1;
    {
        float t;
        t = (f[0] - mean) * rstd * gamma[cb + 0] + beta[cb + 0]; r0.x = x0.x + fmaxf(t, 0.f);
        t = (f[1] - mean) * rstd * gamma[cb + 1] + beta[cb + 1]; r0.y = x0.y + fmaxf(t, 0.f);
        t = (f[2] - mean) * rstd * gamma[cb + 2] + beta[cb + 2]; r0.z = x0.z + fmaxf(t, 0.f);
        t = (f[3] - mean) * rstd * gamma[cb + 3] + beta[cb + 3]; r0.w = x0.w + fmaxf(t, 0.f);
        t = (f[4] - mean) * rstd * gamma[cb + 4] + beta[cb + 4]; r1.x = x1.x + fmaxf(t, 0.f);
        t = (f[5] - mean) * rstd * gamma[cb + 5] + beta[cb + 5]; r1.y = x1.y + fmaxf(t, 0.f);
        t = (f[6] - mean) * rstd * gamma[cb + 6] + beta[cb + 6]; r1.z = x1.z + fmaxf(t, 0.f);
        t = (f[7] - mean) * rstd * gamma[cb + 7] + beta[cb + 7]; r1.w = x1.w + fmaxf(t, 0.f);
    }
    *(float4*)&orow[cb] = r0;
    *(float4*)&orow[cb + 4] = r1;
}

// ---------------- launch ----------------
extern "C" void kernel_launch(void* const* d_in, const int* in_sizes, int n_in,
                              void* d_out, int out_size, void* d_ws, size_t ws_size,
                              hipStream_t stream) {
    const float* x      = (const float*)d_in[0];
    const int*   dmask  = (const int*)d_in[1];
    const int*   steps  = (const int*)d_in[2];
    const float* status = (const float*)d_in[3];
    const float* w_in   = (const float*)d_in[4];
    const float* b_in   = (const float*)d_in[5];
    const float* w_out  = (const float*)d_in[6];
    const float* b_out  = (const float*)d_in[7];
    const float* w_mlp  = (const float*)d_in[8];
    const float* b_mlp  = (const float*)d_in[9];
    const float* gamma  = (const float*)d_in[10];
    const float* beta   = (const float*)d_in[11];
    float* out = (float*)d_out;

    char* ws = (char*)d_ws;
    size_t off = 0;
    auto alloc = [&](size_t bytes) {
        void* ptr = ws + off;
        off = (off + bytes + 255) & ~(size_t)255;
        return ptr;
    };
    __bf16* x_bf    = (__bf16*)alloc((size_t)N_TOK * EDIM * 2);
    __bf16* wqkv_bf = (__bf16*)alloc((size_t)3 * EDIM * EDIM * 2);
    __bf16* wmlp_bf = (__bf16*)alloc((size_t)EDIM * LDCOMB * 2);
    __bf16* woutT_bf= (__bf16*)alloc((size_t)EDIM * EDIM * 2);
    __bf16* weff_bf = (__bf16*)alloc((size_t)EDIM * EDIM * 2);
    __bf16* qs_bf   = (__bf16*)alloc((size_t)N_TOK * EDIM * 2);
    __bf16* ks_bf   = (__bf16*)alloc((size_t)N_TOK * EDIM * 2);
    __bf16* vt_bf   = (__bf16*)alloc((size_t)EDIM * N_TOK * 2);
    __bf16* ctx_bf  = (__bf16*)alloc((size_t)N_TOK * EDIM * 2);
    __bf16* h_bf    = (__bf16*)alloc((size_t)N_TOK * EDIM * 2);
    int*    perm    = (int*)alloc(N_TOK * 4);
    int*    sstep   = (int*)alloc(N_TOK * 4);
    int*    bs_row  = (int*)alloc(N_TOK * 4);
    int*    qinfo   = (int*)alloc(128 * 4);
    __bf16* po      = (__bf16*)alloc((size_t)SPLITK * NHEAD * N_TOK * HD * 2);
    float*  pl      = (float*)alloc((size_t)SPLITK * NHEAD * N_TOK * 4);
    float*  add2    = (float*)alloc(2 * EDIM * 4);
    float*  tv      = (float*)alloc((size_t)NBIN * EDIM * 4);
    __bf16* tmat    = (__bf16*)alloc(128 * 256 * 2);

    // prep: converts + w_out^T + add2 + time-matrix + sort/plan
    prep_kernel<<<NB_PREP, 256, 0, stream>>>(
        x, w_in, w_mlp, w_out, status, b_out, b_mlp, steps,
        x_bf, wqkv_bf, wmlp_bf, woutT_bf, add2, tmat, perm, sstep, bs_row, qinfo);
    // qkv GEMM (direct sorted qs/ks/vt) + weff GEMM + tv GEMM
    gemm2_kernel<<<404, 256, 0, stream>>>(
        x_bf, wqkv_bf, b_in, perm, qs_bf, ks_bf, vt_bf,
        wmlp_bf, woutT_bf, weff_bf, tmat, tv);
    // attention (32x32 MFMA, 2-buffer DMA pipeline, split-K=8, XCD-swizzled h)
    attn_kernel<<<dim3(NQT * NHEAD, SPLITK), 256, 0, stream>>>(
        qs_bf, ks_bf, vt_bf, bs_row, qinfo, po, pl);
    // combine partials -> ctx (original token order, x8 vectorized)
    combine_kernel<<<(N_TOK * EDIM) / 2048, 256, 0, stream>>>(po, pl, perm, ctx_bf);
    // h = ctx @ w_eff^T + add2[dmask] + tv[step]  (64x128 tiles, bf16 out)
    gemm_fused<<<dim3(N_TOK / 64, EDIM / 128), 256, 0, stream>>>(
        ctx_bf, weff_bf, dmask, steps, add2, tv, h_bf);
    // LN + ReLU + residual (bf16 h input)
    ln_kernel<<<N_TOK / 4, 256, 0, stream>>>(h_bf, x, gamma, beta, out);
}

// Round 14
// 175.645 us; speedup vs baseline: 1.1509x; 1.0310x over previous
//
#include <hip/hip_runtime.h>
#include <hip/hip_bf16.h>
#include <math.h>

typedef __bf16 bf16x8 __attribute__((ext_vector_type(8)));
typedef __bf16 bf16x4 __attribute__((ext_vector_type(4)));
typedef float f32x4 __attribute__((ext_vector_type(4)));
typedef float f32x16 __attribute__((ext_vector_type(16)));

#define N_TOK 4096
#define EDIM 512
#define NHEAD 8
#define HD 64
#define LDCOMB 896
#define NBIN 100
#define SPLITK 8
#define BK 64
#define NQT 32   // 128-row q tiles

// prep block partition (cvt blocks process 4 float4s per thread)
#define NU_CVT 816
#define NU_TC 64
#define NU_ADD 128
#define NU_TMAT 128
#define NB_PREP (NU_CVT + NU_TC + NU_ADD + NU_TMAT + 1)

__device__ __forceinline__ unsigned int pk2(float a, float b) {
    union { __bf16 h[2]; unsigned int u; } x;
    x.h[0] = (__bf16)a; x.h[1] = (__bf16)b;
    return x.u;
}

// ---------------- prep: cvt + w_out^T + add2 + time-matrix + sort/plan ----------------
__global__ __launch_bounds__(256) void prep_kernel(
    const float* __restrict__ x, const float* __restrict__ w_in,
    const float* __restrict__ w_mlp, const float* __restrict__ w_out,
    const float* __restrict__ status, const float* __restrict__ out_b,
    const float* __restrict__ mlp_b, const int* __restrict__ steps,
    __bf16* __restrict__ x_bf, __bf16* __restrict__ wqkv_bf,
    __bf16* __restrict__ wmlp_bf, __bf16* __restrict__ woutT_bf,
    float* __restrict__ add2, __bf16* __restrict__ tmat,
    int* __restrict__ perm, int* __restrict__ sstep,
    int* __restrict__ bs_row, int* __restrict__ qinfo) {
    __shared__ float T[64][65];
    __shared__ int hist[NBIN];
    __shared__ int offs[NBIN];
    const int bid = blockIdx.x;
    const int tid = threadIdx.x;
    const int wave = tid >> 6, lane = tid & 63;

    if (bid < NU_CVT) {
        // fp32 -> bf16: x, w_in, w_mlp — 4 float4s per thread (816*1024 = exact total)
        const int n0 = N_TOK * EDIM / 4;
        const int n1 = 3 * EDIM * EDIM / 4;
        #pragma unroll
        for (int k = 0; k < 4; k++) {
            int i = bid * 1024 + k * 256 + tid;
            const float* src; __bf16* dst;
            if (i < n0)           { src = x; dst = x_bf; }
            else if (i < n0 + n1) { i -= n0; src = w_in; dst = wqkv_bf; }
            else                  { i -= n0 + n1; src = w_mlp; dst = wmlp_bf; }
            const float4 v = ((const float4*)src)[i];
            bf16x4 o;
            o[0] = (__bf16)v.x; o[1] = (__bf16)v.y; o[2] = (__bf16)v.z; o[3] = (__bf16)v.w;
            ((bf16x4*)dst)[i] = o;
        }
    } else if (bid < NU_CVT + NU_TC) {
        // transpose+cvt w_out -> woutT[k][m]
        const int b2 = bid - NU_CVT;
        const int m0 = (b2 >> 3) * 64, k0 = (b2 & 7) * 64;
        const int row = tid >> 2, c4 = (tid & 3) * 16;
        #pragma unroll
        for (int i = 0; i < 4; i++) {
            const float4 v = *(const float4*)&w_out[(size_t)(m0 + row) * EDIM + k0 + c4 + i * 4];
            T[row][c4 + i * 4 + 0] = v.x;
            T[row][c4 + i * 4 + 1] = v.y;
            T[row][c4 + i * 4 + 2] = v.z;
            T[row][c4 + i * 4 + 3] = v.w;
        }
        __syncthreads();
        const int kr = tid >> 2, m16 = (tid & 3) * 16;
        bf16x8 o0, o1;
        #pragma unroll
        for (int i = 0; i < 8; i++) o0[i] = (__bf16)T[m16 + i][kr];
        #pragma unroll
        for (int i = 0; i < 8; i++) o1[i] = (__bf16)T[m16 + 8 + i][kr];
        *(bf16x8*)&woutT_bf[(size_t)(k0 + kr) * EDIM + m0 + m16] = o0;
        *(bf16x8*)&woutT_bf[(size_t)(k0 + kr) * EDIM + m0 + m16 + 8] = o1;
    } else if (bid < NU_CVT + NU_TC + NU_ADD) {
        // add2[m][j] = status[m].w_mlp[j,512:640] + mlp_b[j] + w_mlp[j,:512].b_out
        const int j = (bid - NU_CVT - NU_TC) * 4 + wave;
        const float* wr = w_mlp + (size_t)j * LDCOMB;
        const int k8 = lane * 8;
        const float4 wa = *(const float4*)&wr[k8], wb = *(const float4*)&wr[k8 + 4];
        const float4 oa = *(const float4*)&out_b[k8], ob = *(const float4*)&out_b[k8 + 4];
        float b = wa.x * oa.x + wa.y * oa.y + wa.z * oa.z + wa.w * oa.w +
                  wb.x * ob.x + wb.y * ob.y + wb.z * ob.z + wb.w * ob.w;
        const int c2 = lane * 2;
        const float w0 = wr[EDIM + c2], w1 = wr[EDIM + c2 + 1];
        float s0 = status[c2] * w0 + status[c2 + 1] * w1;
        float s1 = status[128 + c2] * w0 + status[129 + c2] * w1;
        #pragma unroll
        for (int m = 1; m < 64; m <<= 1) {
            b += __shfl_xor(b, m);
            s0 += __shfl_xor(s0, m);
            s1 += __shfl_xor(s1, m);
        }
        if (lane == 0) {
            const float bb = b + mlp_b[j];
            add2[j] = s0 + bb;
            add2[EDIM + j] = s1 + bb;
        }
    } else if (bid < NU_CVT + NU_TC + NU_ADD + NU_TMAT) {
        // bf16 time matrix [128][256] (rows >= 100 are padding, masked at tv store)
        const int st = bid - NU_CVT - NU_TC - NU_ADD;
        const int c = tid;
        const int pp = c >> 1;
        const float div = expf((float)(2 * pp) * (-9.210340371976184f / 256.0f));
        const float ang = (float)st * div;
        tmat[st * 256 + c] = (__bf16)((c & 1) ? cosf(ang) : sinf(ang));
    } else {
        // counting sort by step + bs_row + per-qtile plan
        if (tid < NBIN) hist[tid] = 0;
        __syncthreads();
        for (int i = tid; i < N_TOK; i += 256)
            atomicAdd(&hist[min(max(steps[i], 0), NBIN - 1)], 1);
        __syncthreads();
        if (tid == 0) {
            int acc = 0;
            for (int s = 0; s < NBIN; s++) { offs[s] = acc; acc += hist[s]; }
        }
        __syncthreads();
        if (tid < NBIN) hist[tid] = offs[tid];   // immutable copy of bin_start
        __syncthreads();
        for (int i = tid; i < N_TOK; i += 256) {
            const int s = min(max(steps[i], 0), NBIN - 1);
            const int pos = atomicAdd(&offs[s], 1);
            perm[pos] = i;
            sstep[pos] = s;
        }
        __syncthreads();
        for (int q = tid; q < N_TOK; q += 256)
            bs_row[q] = hist[sstep[q]];
        __syncthreads();
        for (int qt = tid; qt < NQT; qt += 256) {
            qinfo[qt * 2] = bs_row[qt * 128] & ~(BK - 1);
            qinfo[qt * 2 + 1] = bs_row[qt * 128 + 127];
        }
    }
}

// ---------------- merged GEMMs v2: BK=64, XOR-swizzled LDS, global_load_lds staging ----------------
// qkv->sorted qs/ks/vt (384) + weff (16) + tv (4)
__global__ __launch_bounds__(256) void gemm2_kernel(const __bf16* __restrict__ x_bf,
                                                    const __bf16* __restrict__ wqkv_bf,
                                                    const float* __restrict__ b_in,
                                                    const int* __restrict__ perm,
                                                    __bf16* __restrict__ qs,
                                                    __bf16* __restrict__ ks,
                                                    __bf16* __restrict__ vt,
                                                    const __bf16* __restrict__ wmlp_bf,
                                                    const __bf16* __restrict__ woutT_bf,
                                                    __bf16* __restrict__ weff_bf,
                                                    const __bf16* __restrict__ tmat,
                                                    float* __restrict__ tv) {
    // As/Bs: [128 rows][64 k] bf16, chunk c (8 elem) of row r stored at c^(r&7).
    __shared__ __attribute__((aligned(16))) union {
        struct { __bf16 As[128 * 64]; __bf16 Bs[128 * 64]; } g;
        __bf16 T[128][72];
    } sm;
    __shared__ int pr[128];
    const int bid = blockIdx.x;
    const int tid = threadIdx.x;
    const int wave = tid >> 6, lane = tid & 63;
    const int wm = (wave >> 1) * 64, wn = (wave & 1) * 64;
    const int lr = lane & 15, lq = lane >> 4;

    const __bf16 *A, *B;
    int lda, ldb, bm, bn, K, mode;
    if (bid < 384) {
        A = x_bf; lda = EDIM; B = wqkv_bf; ldb = EDIM; K = EDIM; mode = 0;
        bm = (bid & 31) * 128; bn = (bid >> 5) * 128;
        if (tid < 128) pr[tid] = perm[bm + tid];
    } else if (bid < 400) {
        const int b2 = bid - 384;
        A = wmlp_bf; lda = LDCOMB; B = woutT_bf; ldb = EDIM; K = EDIM; mode = 1;
        bm = (b2 & 3) * 128; bn = (b2 >> 2) * 128;
    } else {
        const int b3 = bid - 400;
        A = tmat; lda = 256; B = wmlp_bf + 640; ldb = LDCOMB; K = 256; mode = 2;
        bm = 0; bn = b3 * 128;
    }

    const int ro = lane >> 3;
    const int sc = (lane & 7) ^ ro;

    #define GOFF(r, c) (((r) << 6) + ((((c) ^ ((r) & 7))) << 3))

    f32x4 acc[4][4] = {};
    for (int k0 = 0; k0 < K; k0 += 64) {
        __syncthreads();
        #pragma unroll
        for (int i = 0; i < 4; i++) {
            const int g = wave * 4 + i;          // 8-row group 0..15
            const int row = g * 8 + ro;
            const int arow = (mode == 0) ? pr[row] : (bm + row);
            const __bf16* ga = A + (size_t)arow * lda + k0 + sc * 8;
            __builtin_amdgcn_global_load_lds(
                (const __attribute__((address_space(1))) unsigned int*)ga,
                (__attribute__((address_space(3))) unsigned int*)&sm.g.As[g * 512],
                16, 0, 0);
            const __bf16* gb = B + (size_t)(bn + row) * ldb + k0 + sc * 8;
            __builtin_amdgcn_global_load_lds(
                (const __attribute__((address_space(1))) unsigned int*)gb,
                (__attribute__((address_space(3))) unsigned int*)&sm.g.Bs[g * 512],
                16, 0, 0);
        }
        __syncthreads();
        #pragma unroll
        for (int kk = 0; kk < 2; kk++) {
            bf16x8 af[4], bfr[4];
            #pragma unroll
            for (int i = 0; i < 4; i++) {
                af[i]  = *(const bf16x8*)&sm.g.As[GOFF(wm + i * 16 + lr, kk * 4 + lq)];
                bfr[i] = *(const bf16x8*)&sm.g.Bs[GOFF(wn + i * 16 + lr, kk * 4 + lq)];
            }
            #pragma unroll
            for (int i = 0; i < 4; i++)
                #pragma unroll
                for (int j = 0; j < 4; j++)
                    acc[i][j] = __builtin_amdgcn_mfma_f32_16x16x32_bf16(af[i], bfr[j], acc[i][j], 0, 0, 0);
        }
    }
    #undef GOFF

    if (mode == 1) {
        #pragma unroll
        for (int i = 0; i < 4; i++)
            #pragma unroll
            for (int j = 0; j < 4; j++) {
                const int col = bn + wn + j * 16 + lr;
                #pragma unroll
                for (int r = 0; r < 4; r++)
                    weff_bf[(size_t)(bm + wm + i * 16 + lq * 4 + r) * EDIM + col] =
                        (__bf16)acc[i][j][r];
            }
    } else if (mode == 2) {
        #pragma unroll
        for (int i = 0; i < 4; i++)
            #pragma unroll
            for (int j = 0; j < 4; j++) {
                const int col = bn + wn + j * 16 + lr;
                #pragma unroll
                for (int r = 0; r < 4; r++) {
                    const int row = wm + i * 16 + lq * 4 + r;
                    if (row < NBIN) tv[(size_t)row * EDIM + col] = acc[i][j][r];
                }
            }
    } else if (bn < 512) {
        // Q: pre-scale by 1/8*log2(e), sorted rows
        const float SC = 0.125f * 1.44269504f;
        #pragma unroll
        for (int i = 0; i < 4; i++)
            #pragma unroll
            for (int j = 0; j < 4; j++) {
                const int col = bn + wn + j * 16 + lr;
                const float bv = b_in[col];
                #pragma unroll
                for (int r = 0; r < 4; r++)
                    qs[(size_t)(bm + wm + i * 16 + lq * 4 + r) * EDIM + col] =
                        (__bf16)((acc[i][j][r] + bv) * SC);
            }
    } else if (bn < 1024) {
        // K: sorted rows
        #pragma unroll
        for (int i = 0; i < 4; i++)
            #pragma unroll
            for (int j = 0; j < 4; j++) {
                const int col = bn + wn + j * 16 + lr;
                const float bv = b_in[col];
                #pragma unroll
                for (int r = 0; r < 4; r++)
                    ks[(size_t)(bm + wm + i * 16 + lq * 4 + r) * EDIM + (col - 512)] =
                        (__bf16)(acc[i][j][r] + bv);
            }
    } else {
        // V: transpose 128x128 tile via LDS, two 64-col halves -> vt[dim][token]
        #pragma unroll
        for (int half = 0; half < 2; half++) {
            __syncthreads();
            if ((wave & 1) == half) {
                #pragma unroll
                for (int i = 0; i < 4; i++)
                    #pragma unroll
                    for (int j = 0; j < 4; j++) {
                        const float bv = b_in[bn + wn + j * 16 + lr];
                        #pragma unroll
                        for (int r = 0; r < 4; r++)
                            sm.T[wm + i * 16 + lq * 4 + r][j * 16 + lr] =
                                (__bf16)(acc[i][j][r] + bv);
                    }
            }
            __syncthreads();
            for (int u = tid; u < 1024; u += 256) {
                const int d = u & 63, t8 = (u >> 6) * 8;
                bf16x8 v;
                #pragma unroll
                for (int j = 0; j < 8; j++) v[j] = sm.T[t8 + j][d];
                const int dim = (bn - 1024) + half * 64 + d;
                *(bf16x8*)&vt[(size_t)dim * N_TOK + bm + t8] = v;
            }
        }
    }
}

// ---------------- flash attention v6 (R6-verified): 32x32 MFMA, XOR LDS,
// 2-buffer DMA double-buffer, SPLITK=8, 1 barrier per K-tile ----------------
__global__ __launch_bounds__(256, 4) void attn_kernel(const __bf16* __restrict__ qs,
                                                      const __bf16* __restrict__ ks,
                                                      const __bf16* __restrict__ vt,
                                                      const int* __restrict__ bs_row,
                                                      const int* __restrict__ qinfo,
                                                      __bf16* __restrict__ po,
                                                      float* __restrict__ pl) {
    __shared__ __attribute__((aligned(16))) __bf16 KVs[2][2][4096];

    const int h = blockIdx.x & 7;
    const int qtile = blockIdx.x >> 3;
    const int ck = blockIdx.y;
    const int tid = threadIdx.x, wave = tid >> 6, lane = tid & 63;
    const int l31 = lane & 31, hi = lane >> 5;
    const int wq0 = qtile * 128 + wave * 32;

    const int kt0 = qinfo[qtile * 2];
    const int bs_blockmax = qinfo[qtile * 2 + 1];
    const int nt = (N_TOK - kt0) / BK;
    const int kta = kt0 + ((nt * ck) / SPLITK) * BK;
    const int ktb = kt0 + ((nt * (ck + 1)) / SPLITK) * BK;

    bf16x8 aq[4];
    {
        const __bf16* qrow = qs + (size_t)(wq0 + l31) * EDIM + h * HD;
        #pragma unroll
        for (int m = 0; m < 4; m++) aq[m] = *(const bf16x8*)&qrow[m * 16 + hi * 8];
    }
    const int bsq = bs_row[wq0 + l31];

    bf16x8 ones;
    #pragma unroll
    for (int i = 0; i < 8; i++) ones[i] = (__bf16)1.0f;

    f32x16 lacc = {};
    f32x16 o0 = {}, o1 = {};

    const int ro = lane >> 3;
    const int sc = (lane & 7) ^ ro;

    auto stage = [&](int buf, int kt_s) {
        #pragma unroll
        for (int i = 0; i < 2; i++) {
            const int g = wave * 2 + i;
            const __bf16* gk = ks + (size_t)(kt_s + g * 8 + ro) * EDIM + h * HD + sc * 8;
            __builtin_amdgcn_global_load_lds(
                (const __attribute__((address_space(1))) unsigned int*)gk,
                (__attribute__((address_space(3))) unsigned int*)&KVs[buf][0][g * 512],
                16, 0, 0);
            const __bf16* gv = vt + (size_t)(h * HD + g * 8 + ro) * N_TOK + kt_s + sc * 8;
            __builtin_amdgcn_global_load_lds(
                (const __attribute__((address_space(1))) unsigned int*)gv,
                (__attribute__((address_space(3))) unsigned int*)&KVs[buf][1][g * 512],
                16, 0, 0);
        }
    };

    #define LDOFF(r, c) ((r) * 64 + ((((c) ^ ((r) & 7))) << 3))

    if (kta < ktb) stage(0, kta);
    __syncthreads();

    int cur = 0;
    for (int kt = kta; kt < ktb; kt += BK) {
        if (kt + BK < ktb) stage(cur ^ 1, kt + BK);
        const __bf16* Kl = &KVs[cur][0][0];
        const __bf16* Vl = &KVs[cur][1][0];

        __builtin_amdgcn_s_setprio(1);
        #pragma unroll
        for (int t = 0; t < 2; t++) {
            f32x16 s = {};
            #pragma unroll
            for (int m = 0; m < 4; m++) {
                const bf16x8 kb = *(const bf16x8*)&Kl[LDOFF(t * 32 + l31, 2 * m + hi)];
                s = __builtin_amdgcn_mfma_f32_32x32x16_bf16(kb, aq[m], s, 0, 0, 0);
            }
            if (kt < bs_blockmax) {
                const int tokb = kt + t * 32 + 4 * hi;
                #pragma unroll
                for (int r = 0; r < 16; r++) {
                    const int tok = tokb + (r & 3) + 8 * (r >> 2);
                    if (tok < bsq) s[r] = -1e9f;
                }
            }
            unsigned int pk[8];
            #pragma unroll
            for (int m = 0; m < 8; m++)
                pk[m] = pk2(exp2f(s[2 * m]), exp2f(s[2 * m + 1]));
            asm("v_permlane32_swap_b32 %0, %1" : "+v"(pk[0]), "+v"(pk[2]));
            asm("v_permlane32_swap_b32 %0, %1" : "+v"(pk[1]), "+v"(pk[3]));
            asm("v_permlane32_swap_b32 %0, %1" : "+v"(pk[4]), "+v"(pk[6]));
            asm("v_permlane32_swap_b32 %0, %1" : "+v"(pk[5]), "+v"(pk[7]));
            union { unsigned int u[4]; bf16x8 v; } f0, f1;
            f0.u[0] = pk[0]; f0.u[1] = pk[1]; f0.u[2] = pk[2]; f0.u[3] = pk[3];
            f1.u[0] = pk[4]; f1.u[1] = pk[5]; f1.u[2] = pk[6]; f1.u[3] = pk[7];
            lacc = __builtin_amdgcn_mfma_f32_32x32x16_bf16(ones, f0.v, lacc, 0, 0, 0);
            lacc = __builtin_amdgcn_mfma_f32_32x32x16_bf16(ones, f1.v, lacc, 0, 0, 0);
            #pragma unroll
            for (int h2 = 0; h2 < 2; h2++) {
                const bf16x8 va = *(const bf16x8*)&Vl[LDOFF(l31, 4 * t + 2 * h2 + hi)];
                const bf16x8 vb = *(const bf16x8*)&Vl[LDOFF(32 + l31, 4 * t + 2 * h2 + hi)];
                const bf16x8 pf = h2 ? f1.v : f0.v;
                o0 = __builtin_amdgcn_mfma_f32_32x32x16_bf16(va, pf, o0, 0, 0, 0);
                o1 = __builtin_amdgcn_mfma_f32_32x32x16_bf16(vb, pf, o1, 0, 0, 0);
            }
        }
        __builtin_amdgcn_s_setprio(0);
        __syncthreads();
        cur ^= 1;
    }
    #undef LDOFF

    __bf16* pob = po + (((size_t)(ck * NHEAD + h) * N_TOK) + wq0 + l31) * HD;
    #pragma unroll
    for (int rg = 0; rg < 4; rg++) {
        bf16x4 ova, ovb;
        #pragma unroll
        for (int r = 0; r < 4; r++) { ova[r] = (__bf16)o0[rg * 4 + r]; ovb[r] = (__bf16)o1[rg * 4 + r]; }
        *(bf16x4*)&pob[rg * 8 + 4 * hi] = ova;
        *(bf16x4*)&pob[32 + rg * 8 + 4 * hi] = ovb;
    }
    if (hi == 0)
        pl[(size_t)(ck * NHEAD + h) * N_TOK + wq0 + l31] = lacc[0];
}

// ---------------- combine split-K partials (x8 vectorized), scatter to ctx ----------------
__global__ __launch_bounds__(256) void combine_kernel(const __bf16* __restrict__ po,
                                                      const float* __restrict__ pl,
                                                      const int* __restrict__ perm,
                                                      __bf16* __restrict__ ctx) {
    const int e = blockIdx.x * 256 + threadIdx.x;   // over 4096*64 col8-groups
    const int q = e >> 6;
    const int col = (e & 63) * 8;
    const int h = col >> 6, d = col & 63;
    float s[8] = {};
    float l = 0.f;
    #pragma unroll
    for (int c = 0; c < SPLITK; c++) {
        const bf16x8 v = *(const bf16x8*)&po[(((size_t)(c * NHEAD + h) * N_TOK) + q) * HD + d];
        #pragma unroll
        for (int j = 0; j < 8; j++) s[j] += (float)v[j];
        l += pl[(size_t)(c * NHEAD + h) * N_TOK + q];
    }
    const float rl = 1.0f / l;
    bf16x8 o;
    #pragma unroll
    for (int j = 0; j < 8; j++) o[j] = (__bf16)(s[j] * rl);
    *(bf16x8*)&ctx[(size_t)perm[q] * EDIM + col] = o;
}

// ---------------- fused final GEMM v3: 64x128 tiles, BK=64, XOR-swizzled LDS,
// global_load_lds staging (gemm2-verified pattern); bf16 h output ----------------
// h = ctx @ weff^T + add2[dmask] + tv[step]
__global__ __launch_bounds__(256) void gemm_fused(const __bf16* __restrict__ A,
                                                  const __bf16* __restrict__ B,
                                                  const int* __restrict__ dmask,
                                                  const int* __restrict__ steps,
                                                  const float* __restrict__ add2,
                                                  const float* __restrict__ tv,
                                                  __bf16* __restrict__ C) {
    // As2: [64 rows][64 k], Bs2: [128 rows][64 k]; chunk c of row r stored at c^(r&7)
    __shared__ __attribute__((aligned(16))) __bf16 As2[64 * 64];
    __shared__ __attribute__((aligned(16))) __bf16 Bs2[128 * 64];
    const int tid = threadIdx.x;
    const int wave = tid >> 6, lane = tid & 63;
    const int wm = (wave >> 1) * 32, wn = (wave & 1) * 64;
    const int bm = blockIdx.x * 64, bn = blockIdx.y * 128;
    const int lr = lane & 15, lq = lane >> 4;
    const int ro = lane >> 3;
    const int sc = (lane & 7) ^ ro;

    #define GOFF(r, c) (((r) << 6) + ((((c) ^ ((r) & 7))) << 3))

    f32x4 acc[2][4] = {};
    for (int k0 = 0; k0 < EDIM; k0 += 64) {
        __syncthreads();
        // A: 8 groups of 8 rows; wave w stages groups {2w, 2w+1}
        #pragma unroll
        for (int i = 0; i < 2; i++) {
            const int g = wave * 2 + i;
            const __bf16* ga = A + (size_t)(bm + g * 8 + ro) * EDIM + k0 + sc * 8;
            __builtin_amdgcn_global_load_lds(
                (const __attribute__((address_space(1))) unsigned int*)ga,
                (__attribute__((address_space(3))) unsigned int*)&As2[g * 512],
                16, 0, 0);
        }
        // B: 16 groups of 8 rows; wave w stages groups {4w..4w+3}
        #pragma unroll
        for (int i = 0; i < 4; i++) {
            const int g = wave * 4 + i;
            const __bf16* gb = B + (size_t)(bn + g * 8 + ro) * EDIM + k0 + sc * 8;
            __builtin_amdgcn_global_load_lds(
                (const __attribute__((address_space(1))) unsigned int*)gb,
                (__attribute__((address_space(3))) unsigned int*)&Bs2[g * 512],
                16, 0, 0);
        }
        __syncthreads();
        #pragma unroll
        for (int kk = 0; kk < 2; kk++) {
            bf16x8 af[2], bfr[4];
            #pragma unroll
            for (int i = 0; i < 2; i++)
                af[i] = *(const bf16x8*)&As2[GOFF(wm + i * 16 + lr, kk * 4 + lq)];
            #pragma unroll
            for (int j = 0; j < 4; j++)
                bfr[j] = *(const bf16x8*)&Bs2[GOFF(wn + j * 16 + lr, kk * 4 + lq)];
            #pragma unroll
            for (int i = 0; i < 2; i++)
                #pragma unroll
                for (int j = 0; j < 4; j++)
                    acc[i][j] = __builtin_amdgcn_mfma_f32_16x16x32_bf16(af[i], bfr[j], acc[i][j], 0, 0, 0);
        }
    }
    #undef GOFF

    int dmr[2][4], str[2][4];
    #pragma unroll
    for (int i = 0; i < 2; i++)
        #pragma unroll
        for (int r = 0; r < 4; r++) {
            const int row = bm + wm + i * 16 + lq * 4 + r;
            dmr[i][r] = dmask[row];
            str[i][r] = min(max(steps[row], 0), NBIN - 1);
        }
    #pragma unroll
    for (int i = 0; i < 2; i++)
        #pragma unroll
        for (int j = 0; j < 4; j++) {
            const int col = bn + wn + j * 16 + lr;
            #pragma unroll
            for (int r = 0; r < 4; r++) {
                const int row = bm + wm + i * 16 + lq * 4 + r;
                C[(size_t)row * EDIM + col] = (__bf16)(acc[i][j][r]
                    + add2[dmr[i][r] * EDIM + col] + tv[str[i][r] * EDIM + col]);
            }
        }
}

// ---------------- LayerNorm + ReLU + residual (bf16 h input) ----------------
__global__ __launch_bounds__(256) void ln_kernel(const __bf16* __restrict__ h,
                                                 const float* __restrict__ x,
                                                 const float* __restrict__ gamma,
                                                 const float* __restrict__ beta,
                                                 float* __restrict__ out) {
    const int row = blockIdx.x * 4 + (threadIdx.x >> 6);
    const int lane = threadIdx.x & 63;
    const __bf16* hr = h + (size_t)row * EDIM;
    const bf16x8 hv = *(const bf16x8*)&hr[lane * 8];
    float f[8];
    float sum = 0.f, sq = 0.f;
    #pragma unroll
    for (int i = 0; i < 8; i++) {
        f[i] = (float)hv[i];
        sum += f[i];
        sq += f[i] * f[i];
    }
    #pragma unroll
    for (int m = 1; m < 64; m <<= 1) {
        sum += __shfl_xor(sum, m);
        sq  += __shfl_xor(sq, m);
    }
    const float mean = sum * (1.0f / EDIM);
    const float var = sq * (1.0f / EDIM) - mean * mean;
    const float rstd = rsqrtf(var + 1e-5f);
    const float* xr = x + (size_t)row * EDIM;
    float* orow = out + (size_t)row * EDIM;
    const int cb = lane * 8;
    const float4 x0 = *(const float4*)&xr[cb];
    const float4 x1 = *(const float4*)&xr[cb + 4];
    float4 r0, r1;
    {
        float t;
        t = (f[0] - mean) * rstd * gamma[cb + 0] + beta[cb + 0]; r0.x = x0.x + fmaxf(t, 0.f);
        t = (f[1] - mean) * rstd * gamma[cb + 1] + beta[cb + 1]; r0.y = x0.y + fmaxf(t, 0.f);
        t = (f[2] - mean) * rstd * gamma[cb + 2] + beta[cb + 2]; r0.z = x0.z + fmaxf(t, 0.f);
        t = (f[3] - mean) * rstd * gamma[cb + 3] + beta[cb + 3]; r0.w = x0.w + fmaxf(t, 0.f);
        t = (f[4] - mean) * rstd * gamma[cb + 4] + beta[cb + 4]; r1.x = x1.x + fmaxf(t, 0.f);
        t = (f[5] - mean) * rstd * gamma[cb + 5] + beta[cb + 5]; r1.y = x1.y + fmaxf(t, 0.f);
        t = (f[6] - mean) * rstd * gamma[cb + 6] + beta[cb + 6]; r1.z = x1.z + fmaxf(t, 0.f);
        t = (f[7] - mean) * rstd * gamma[cb + 7] + beta[cb + 7]; r1.w = x1.w + fmaxf(t, 0.f);
    }
    *(float4*)&orow[cb] = r0;
    *(float4*)&orow[cb + 4] = r1;
}

// ---------------- launch ----------------
extern "C" void kernel_launch(void* const* d_in, const int* in_sizes, int n_in,
                              void* d_out, int out_size, void* d_ws, size_t ws_size,
                              hipStream_t stream) {
    const float* x      = (const float*)d_in[0];
    const int*   dmask  = (const int*)d_in[1];
    const int*   steps  = (const int*)d_in[2];
    const float* status = (const float*)d_in[3];
    const float* w_in   = (const float*)d_in[4];
    const float* b_in   = (const float*)d_in[5];
    const float* w_out  = (const float*)d_in[6];
    const float* b_out  = (const float*)d_in[7];
    const float* w_mlp  = (const float*)d_in[8];
    const float* b_mlp  = (const float*)d_in[9];
    const float* gamma  = (const float*)d_in[10];
    const float* beta   = (const float*)d_in[11];
    float* out = (float*)d_out;

    char* ws = (char*)d_ws;
    size_t off = 0;
    auto alloc = [&](size_t bytes) {
        void* ptr = ws + off;
        off = (off + bytes + 255) & ~(size_t)255;
        return ptr;
    };
    __bf16* x_bf    = (__bf16*)alloc((size_t)N_TOK * EDIM * 2);
    __bf16* wqkv_bf = (__bf16*)alloc((size_t)3 * EDIM * EDIM * 2);
    __bf16* wmlp_bf = (__bf16*)alloc((size_t)EDIM * LDCOMB * 2);
    __bf16* woutT_bf= (__bf16*)alloc((size_t)EDIM * EDIM * 2);
    __bf16* weff_bf = (__bf16*)alloc((size_t)EDIM * EDIM * 2);
    __bf16* qs_bf   = (__bf16*)alloc((size_t)N_TOK * EDIM * 2);
    __bf16* ks_bf   = (__bf16*)alloc((size_t)N_TOK * EDIM * 2);
    __bf16* vt_bf   = (__bf16*)alloc((size_t)EDIM * N_TOK * 2);
    __bf16* ctx_bf  = (__bf16*)alloc((size_t)N_TOK * EDIM * 2);
    __bf16* h_bf    = (__bf16*)alloc((size_t)N_TOK * EDIM * 2);
    int*    perm    = (int*)alloc(N_TOK * 4);
    int*    sstep   = (int*)alloc(N_TOK * 4);
    int*    bs_row  = (int*)alloc(N_TOK * 4);
    int*    qinfo   = (int*)alloc(128 * 4);
    __bf16* po      = (__bf16*)alloc((size_t)SPLITK * NHEAD * N_TOK * HD * 2);
    float*  pl      = (float*)alloc((size_t)SPLITK * NHEAD * N_TOK * 4);
    float*  add2    = (float*)alloc(2 * EDIM * 4);
    float*  tv      = (float*)alloc((size_t)NBIN * EDIM * 4);
    __bf16* tmat    = (__bf16*)alloc(128 * 256 * 2);

    // prep: converts + w_out^T + add2 + time-matrix + sort/plan
    prep_kernel<<<NB_PREP, 256, 0, stream>>>(
        x, w_in, w_mlp, w_out, status, b_out, b_mlp, steps,
        x_bf, wqkv_bf, wmlp_bf, woutT_bf, add2, tmat, perm, sstep, bs_row, qinfo);
    // qkv GEMM (direct sorted qs/ks/vt) + weff GEMM + tv GEMM
    gemm2_kernel<<<404, 256, 0, stream>>>(
        x_bf, wqkv_bf, b_in, perm, qs_bf, ks_bf, vt_bf,
        wmlp_bf, woutT_bf, weff_bf, tmat, tv);
    // attention (32x32 MFMA, 2-buffer DMA pipeline, split-K=8, XCD-swizzled h)
    attn_kernel<<<dim3(NQT * NHEAD, SPLITK), 256, 0, stream>>>(
        qs_bf, ks_bf, vt_bf, bs_row, qinfo, po, pl);
    // combine partials -> ctx (original token order, x8 vectorized)
    combine_kernel<<<(N_TOK * EDIM) / 2048, 256, 0, stream>>>(po, pl, perm, ctx_bf);
    // h = ctx @ w_eff^T + add2[dmask] + tv[step]  (64x128 tiles, BK=64 DMA, bf16 out)
    gemm_fused<<<dim3(N_TOK / 64, EDIM / 128), 256, 0, stream>>>(
        ctx_bf, weff_bf, dmask, steps, add2, tv, h_bf);
    // LN + ReLU + residual (bf16 h input)
    ln_kernel<<<N_TOK / 4, 256, 0, stream>>>(h_bf, x, gamma, beta, out);
}